// Round 4
// baseline (557.000 us; speedup 1.0000x reference)
//
#include <hip/hip_runtime.h>
#include <hip/hip_bf16.h>
#include <math.h>

typedef __attribute__((ext_vector_type(8))) short short8;   // 8 x bf16 (4 VGPRs)
typedef __attribute__((ext_vector_type(4))) float floatx4;  // MFMA C/D frag

static __device__ __forceinline__ unsigned short f2bf(float f) {
    unsigned int u = __float_as_uint(f);
    unsigned int r = (u + 0x7fffu + ((u >> 16) & 1u)) >> 16;   // RNE
    return (unsigned short)r;
}

// packed fp32x2 -> bf16x2 (RNE), single VALU inst (no builtin on gfx950)
static __device__ __forceinline__ unsigned int pk_bf16(float lo, float hi) {
    unsigned int r;
    asm("v_cvt_pk_bf16_f32 %0, %1, %2" : "=v"(r) : "v"(lo), "v"(hi));
    return r;
}

// async 16B global -> LDS copy (lds dest = wave-uniform base + lane*16)
static __device__ __forceinline__ void g2l16(const void* g, void* l) {
    __builtin_amdgcn_global_load_lds(
        (const __attribute__((address_space(1))) unsigned int*)g,
        (__attribute__((address_space(3))) unsigned int*)l,
        16, 0, 0);
}

// ---------------------------------------------------------------------------
// Grouped bf16 MFMA GEMM, double-buffered, optional split-K.
//   C[M,N] = A[M,K] @ W[N,K]^T
// A either fp32 (converted during staging via v_cvt_pk_bf16_f32; depth-2
// register pipeline with COUNTED vmcnt barrier so A-loads stay in flight
// across the barrier) or bf16 (async g2l16 path, plain __syncthreads).
// ksplit==1: epilogue applies optional bias + BN + ReLU, writes fp32/bf16.
// ksplit>1 : each k-chunk block atomicAdds its fp32 partial into Cf
//            (Cf pre-zeroed); BN/bias done by bn_finalize.
// Tiles: 128x128, 4 waves, each wave a 64x64 quadrant of 16x16x32 MFMAs.
//
// vmcnt FIFO discipline (fp32-A path), per wave per iteration:
//   issue: [g2l16 W x2] (pinned oldest) ... convert (compiler waits vmcnt(2)
//   = retires the 4 A-loads of the PREVIOUS iter) ... issue [A-load x4]
//   (pinned newest) ... MFMA ... s_waitcnt vmcnt(4) retires exactly the 2
//   g2l16; the 4 A-loads cross the s_barrier still in flight.
// ---------------------------------------------------------------------------
struct GDesc {
    const float*          Af;    // fp32 A (or null)
    const unsigned short* Ab;    // bf16 A (or null)
    const unsigned short* W;     // bf16 W, row stride = K
    float*          Cf;          // fp32 out / partial accum (or null)
    unsigned short* Cb;          // bf16 out (or null)
    const float *bias, *g, *b, *m, *v;
    int M, N, K;                 // K = padded to mult of 32 (W stride, LDS tiles)
    int Kreal;                   // A row stride / true K (= K unless padded)
    int fuse;                    // 1: BN+ReLU (ksplit==1 only)
    int nbx;                     // N / 128
    int block0;                  // first flat block id of this group
    int nbb;                     // blocks per k-chunk = nbx * (M/128)
    int ksplit;                  // #k-chunks (1 = no split)
};
struct GArgs { GDesc g[3]; int n; };

__global__ __launch_bounds__(256)
void gemm_grouped(GArgs ga)
{
    __shared__ unsigned short As[2][4096];   // 128 rows x 32 k (bf16)
    __shared__ unsigned short Bs[2][4096];

    const int bid = blockIdx.x;
    int gi = 0;
    #pragma unroll
    for (int i = 1; i < 3; ++i)
        if (i < ga.n && bid >= ga.g[i].block0) gi = i;
    const GDesc d = ga.g[gi];

    int local = bid - d.block0;
    int kc = 0;
    int Kc = d.K;
    if (d.ksplit > 1) {
        Kc = d.K / d.ksplit;
        kc = local / d.nbb;
        local -= kc * d.nbb;
    }
    const int kbeg = kc * Kc;
    const int bx = local % d.nbx;
    const int by = local / d.nbx;
    const int row0 = by * 128;
    const int col0 = bx * 128;

    const int tid  = threadIdx.x;
    const int wave = tid >> 6;
    const int lane = tid & 63;
    const int qd   = lane >> 4;
    const int ln   = lane & 15;
    const int wr   = (wave >> 1) * 64;
    const int wc   = (wave & 1) * 64;

    // g2l16 chunk mapping: chunk c -> row c>>2, k-offset (c&3)*8
    const int c0 = wave * 128 + lane;
    const int c1 = c0 + 64;
    const int r0 = c0 >> 2, k0 = (c0 & 3) * 8;
    const int r1 = c1 >> 2, k1 = (c1 & 3) * 8;

    // fp32 staging mapping: pass p covers rows p*32..p*32+31
    const int sr = tid >> 3;          // 0..31
    const int sc = (tid & 7) * 4;     // 0,4,..,28

    const bool afp = (d.Af != nullptr);
    const int niter = Kc >> 5;

    floatx4 acc[4][4];
    #pragma unroll
    for (int i = 0; i < 4; ++i)
        #pragma unroll
        for (int j = 0; j < 4; ++j) acc[i][j] = (floatx4){0.f, 0.f, 0.f, 0.f};

    // ---- prologue: stage tile 0 into buffer 0; issue tile-1 A loads ----
    g2l16(d.W + (size_t)(col0 + r0) * d.K + kbeg + k0, &Bs[0][(size_t)wave * 1024]);
    g2l16(d.W + (size_t)(col0 + r1) * d.K + kbeg + k1, &Bs[0][(size_t)wave * 1024 + 512]);
    __builtin_amdgcn_sched_barrier(0);     // keep W g2l16 oldest in vmcnt FIFO
    float4 areg[4];
    if (afp) {
        #pragma unroll
        for (int p = 0; p < 4; ++p) {
            float4 v = (kbeg + sc < d.Kreal)
                ? *(const float4*)(d.Af + (size_t)(row0 + p * 32 + sr) * d.Kreal + kbeg + sc)
                : (float4){0.f, 0.f, 0.f, 0.f};
            uint2 o = { pk_bf16(v.x, v.y), pk_bf16(v.z, v.w) };
            *(uint2*)&As[0][(p * 32 + sr) * 32 + sc] = o;
        }
        // compiler's wait for the converts above necessarily drains vmcnt(0)
        // (A-loads are newest in FIFO) -> Bs[0] g2l16 also complete here.
        if (niter > 1) {
            const int kg = kbeg + 32;
            #pragma unroll
            for (int p = 0; p < 4; ++p)
                areg[p] = (kg + sc < d.Kreal)
                    ? *(const float4*)(d.Af + (size_t)(row0 + p * 32 + sr) * d.Kreal + kg + sc)
                    : (float4){0.f, 0.f, 0.f, 0.f};
        }
        asm volatile("s_waitcnt lgkmcnt(0)" ::: "memory");
        __builtin_amdgcn_sched_barrier(0);
        __builtin_amdgcn_s_barrier();      // A(1) loads stay in flight
    } else {
        g2l16(d.Ab + (size_t)(row0 + r0) * d.K + kbeg + k0, &As[0][(size_t)wave * 1024]);
        g2l16(d.Ab + (size_t)(row0 + r1) * d.K + kbeg + k1, &As[0][(size_t)wave * 1024 + 512]);
        __syncthreads();
    }

    int cur = 0;
    for (int it = 0; it < niter; ++it) {
        const int nxt = cur ^ 1;
        const bool pf = (it + 1 < niter);

        if (pf) {
            const int kg = kbeg + (it + 1) * 32;
            g2l16(d.W + (size_t)(col0 + r0) * d.K + kg + k0, &Bs[nxt][(size_t)wave * 1024]);
            g2l16(d.W + (size_t)(col0 + r1) * d.K + kg + k1, &Bs[nxt][(size_t)wave * 1024 + 512]);
            __builtin_amdgcn_sched_barrier(0);   // pin g2l16 before A-loads in FIFO
            if (afp) {
                // convert tile it+1 (loaded last iteration; compiler emits a
                // counted vmcnt that leaves the 2 g2l16 outstanding)
                #pragma unroll
                for (int p = 0; p < 4; ++p) {
                    uint2 o = { pk_bf16(areg[p].x, areg[p].y),
                                pk_bf16(areg[p].z, areg[p].w) };
                    *(uint2*)&As[nxt][(p * 32 + sr) * 32 + sc] = o;
                }
                // always issue 4 A-loads to keep the vmcnt schedule invariant
                // (dummy in-bounds reload of kbeg on the tail iteration)
                const int kg2 = (it + 2 < niter) ? kbeg + (it + 2) * 32 : kbeg;
                #pragma unroll
                for (int p = 0; p < 4; ++p)
                    areg[p] = (kg2 + sc < d.Kreal)
                        ? *(const float4*)(d.Af + (size_t)(row0 + p * 32 + sr) * d.Kreal + kg2 + sc)
                        : (float4){0.f, 0.f, 0.f, 0.f};
            } else {
                g2l16(d.Ab + (size_t)(row0 + r0) * d.K + kg + k0, &As[nxt][(size_t)wave * 1024]);
                g2l16(d.Ab + (size_t)(row0 + r1) * d.K + kg + k1, &As[nxt][(size_t)wave * 1024 + 512]);
            }
        }

        // ---- compute on current buffer ----
        short8 a[4], b[4];
        #pragma unroll
        for (int i = 0; i < 4; ++i)
            a[i] = *(const short8*)&As[cur][(wr + i * 16 + ln) * 32 + qd * 8];
        #pragma unroll
        for (int j = 0; j < 4; ++j)
            b[j] = *(const short8*)&Bs[cur][(wc + j * 16 + ln) * 32 + qd * 8];
        #pragma unroll
        for (int i = 0; i < 4; ++i)
            #pragma unroll
            for (int j = 0; j < 4; ++j)
                acc[i][j] = __builtin_amdgcn_mfma_f32_16x16x32_bf16(
                                a[i], b[j], acc[i][j], 0, 0, 0);

        if (afp) {
            // drain the 2 g2l16 (oldest), keep the 4 A-loads flying across
            // the barrier; flush ds_writes for the buffer swap
            asm volatile("s_waitcnt vmcnt(4) lgkmcnt(0)" ::: "memory");
            __builtin_amdgcn_sched_barrier(0);
            __builtin_amdgcn_s_barrier();
        } else {
            __syncthreads();
        }
        cur = nxt;
    }

    // ---- epilogue: C/D layout col = lane&15, row = quad*4 + reg ----
    if (d.ksplit > 1) {
        // fp32 partial accumulation; BN/bias deferred to bn_finalize
        #pragma unroll
        for (int j = 0; j < 4; ++j) {
            const int col = col0 + wc + j * 16 + ln;
            #pragma unroll
            for (int i = 0; i < 4; ++i) {
                #pragma unroll
                for (int r = 0; r < 4; ++r) {
                    const int row = row0 + wr + i * 16 + qd * 4 + r;
                    atomicAdd(&d.Cf[(size_t)row * d.N + col], acc[i][j][r]);
                }
            }
        }
        return;
    }

    #pragma unroll
    for (int j = 0; j < 4; ++j) {
        const int col = col0 + wc + j * 16 + ln;
        float add = d.bias ? d.bias[col] : 0.f;
        float scale = 1.f, shift = 0.f;
        if (d.fuse) {
            scale = d.g[col] * rsqrtf(d.v[col] + 1e-5f);
            shift = d.b[col] - d.m[col] * scale;
        }
        #pragma unroll
        for (int i = 0; i < 4; ++i) {
            #pragma unroll
            for (int r = 0; r < 4; ++r) {
                const int row = row0 + wr + i * 16 + qd * 4 + r;
                float vv = acc[i][j][r] + add;
                if (d.fuse) vv = fmaxf(vv * scale + shift, 0.f);
                if (d.Cf) d.Cf[(size_t)row * d.N + col] = vv;
                if (d.Cb) d.Cb[(size_t)row * d.N + col] = f2bf(vv);
            }
        }
    }
}

// ---------------------------------------------------------------------------
// Prep: all 7 weight matrices fp32 -> bf16 (fc padded) + zero-fill the
// split-K partial-accumulator region (replaces hipMemsetAsync dispatch)
// ---------------------------------------------------------------------------
struct WSeg { const float* src; unsigned short* dst; int Kreal; int Kp; };
struct WArgs { WSeg s[7]; int off[8]; float4* zdst; int zn; };

__global__ __launch_bounds__(256)
void cvt_weights(WArgs wa)
{
    int i = blockIdx.x * 256 + threadIdx.x;
    if (i >= wa.off[7]) {
        int z = i - wa.off[7];
        if (z < wa.zn) wa.zdst[z] = (float4){0.f, 0.f, 0.f, 0.f};
        return;
    }
    int s = 0;
    #pragma unroll
    for (int j = 1; j < 7; ++j) if (i >= wa.off[j]) s = j;
    const WSeg sg = wa.s[s];
    const int li = i - wa.off[s];
    const int r = li / sg.Kp, c = li - r * sg.Kp;
    sg.dst[li] = (c < sg.Kreal) ? f2bf(sg.src[(size_t)r * sg.Kreal + c])
                                : (unsigned short)0;
}

// ---------------------------------------------------------------------------
// (bias) + BN + ReLU over split-K fp32 partial sums (vec4 per thread);
// writes bf16 (dstb) and/or fp32 (dstf). Zeroes the (dead) source region so
// it can be reused as a pre-zeroed atomic accumulator by the next GEMM.
// ---------------------------------------------------------------------------
struct FSeg { float* src; unsigned short* dstb; float* dstf;
              const float *bias, *g, *b, *m, *v; int N; };
struct FArgs { FSeg s[3]; int off[4]; };   // offsets in vec4 units

__global__ __launch_bounds__(256)
void bn_finalize(FArgs fa)
{
    int i = blockIdx.x * 256 + threadIdx.x;
    if (i >= fa.off[3]) return;
    int s = 0;
    #pragma unroll
    for (int j = 1; j < 3; ++j) if (i >= fa.off[j]) s = j;
    const FSeg sg = fa.s[s];
    const int li = i - fa.off[s];
    const int e = li * 4;
    const int col = e % sg.N;              // N % 4 == 0 -> cols col..col+3
    float4 vv = *(const float4*)(sg.src + e);
    float4 fo;
    ushort4 o;
    #pragma unroll
    for (int r = 0; r < 4; ++r) {
        float x = (&vv.x)[r];
        if (sg.bias) x += sg.bias[col + r];
        float sc = sg.g[col + r] * rsqrtf(sg.v[col + r] + 1e-5f);
        float sh = sg.b[col + r] - sg.m[col + r] * sc;
        x = fmaxf(x * sc + sh, 0.f);
        (&fo.x)[r] = x;
        ((unsigned short*)&o)[r] = f2bf(x);
    }
    if (sg.dstb) *(ushort4*)(sg.dstb + e) = o;
    if (sg.dstf) *(float4*)(sg.dstf + e) = fo;
    *(float4*)(sg.src + e) = (float4){0.f, 0.f, 0.f, 0.f};   // re-arm accum
}

// ---------------------------------------------------------------------------
// Fused attention (per batch row): channel attn (N=10) + spatial conv k=7 +
// weighted sum over N -> xsum[b][688]
// ---------------------------------------------------------------------------
__global__ __launch_bounds__(256)
void attn_kernel(const float* __restrict__ obj, const float* __restrict__ bbox,
                 const float* __restrict__ word, const float* __restrict__ sen,
                 const float* __restrict__ bod,
                 const float* __restrict__ Wc1, const float* __restrict__ Wc2,
                 const float* __restrict__ Wsa,
                 float* __restrict__ xsum_out)
{
    const int b = blockIdx.x;
    const int tid = threadIdx.x;

    __shared__ float xs[10][688];
    __shared__ float s0[688], s1[688];
    __shared__ float avec[10], mvec[10], att[10];
    __shared__ float cw[14], c1[50], c2[50];

    if (tid < 14) cw[tid] = Wsa[tid];
    if (tid < 50) { c1[tid] = Wc1[tid]; c2[tid] = Wc2[tid]; }

    for (int n = 0; n < 10; ++n) {
        const float* o  = obj  + ((size_t)b * 10 + n) * 128;
        const float* bx = bbox + ((size_t)b * 10 + n) * 4;
        const float* w  = word + ((size_t)b * 10 + n) * 300;
        const float* s  = sen  + ((size_t)b * 10 + n) * 128;
        const float* bo = bod  + (size_t)b * 128;
        for (int c = tid; c < 688; c += 256) {
            float v;
            if      (c < 128) v = o[c];
            else if (c < 132) v = bx[c - 128];
            else if (c < 432) v = w[c - 132];
            else if (c < 560) v = s[c - 432];
            else              v = bo[c - 560];
            xs[n][c] = v;
        }
    }
    __syncthreads();

    // wave-parallel per-row mean/max: wave w handles rows w, w+4, w+8
    {
        const int wv = tid >> 6, ln2 = tid & 63;
        for (int n = wv; n < 10; n += 4) {
            float sm = 0.f, mx = -INFINITY;
            for (int c = ln2; c < 688; c += 64) {
                float v = xs[n][c];
                sm += v; mx = fmaxf(mx, v);
            }
            #pragma unroll
            for (int off = 32; off > 0; off >>= 1) {
                sm += __shfl_down(sm, off);
                mx = fmaxf(mx, __shfl_down(mx, off));
            }
            if (ln2 == 0) { avec[n] = sm * (1.f / 688.f); mvec[n] = mx; }
        }
    }
    __syncthreads();

    if (tid == 0) {
        float ha[5], hm[5];
        #pragma unroll
        for (int i = 0; i < 5; ++i) {
            float sa_ = 0.f, sm_ = 0.f;
            #pragma unroll
            for (int j = 0; j < 10; ++j) {
                sa_ += c1[i * 10 + j] * avec[j];
                sm_ += c1[i * 10 + j] * mvec[j];
            }
            ha[i] = fmaxf(sa_, 0.f);
            hm[i] = fmaxf(sm_, 0.f);
        }
        #pragma unroll
        for (int j = 0; j < 10; ++j) {
            float v = 0.f;
            #pragma unroll
            for (int i = 0; i < 5; ++i) v += c2[j * 5 + i] * (ha[i] + hm[i]);
            att[j] = 1.f / (1.f + expf(-v));
        }
    }
    __syncthreads();

    for (int c = tid; c < 688; c += 256) {
        float sm = 0.f, mx = -INFINITY;
        #pragma unroll
        for (int n = 0; n < 10; ++n) {
            float v = xs[n][c] * att[n];
            xs[n][c] = v;
            sm += v; mx = fmaxf(mx, v);
        }
        s0[c] = sm * 0.1f;
        s1[c] = mx;
    }
    __syncthreads();

    for (int c = tid; c < 688; c += 256) {
        float sa = 0.f;
        #pragma unroll
        for (int j = 0; j < 7; ++j) {
            int cc = c + j - 3;
            if (cc >= 0 && cc < 688)
                sa += cw[j] * s0[cc] + cw[7 + j] * s1[cc];
        }
        float sig = 1.f / (1.f + expf(-sa));
        float sm = 0.f;
        #pragma unroll
        for (int n = 0; n < 10; ++n) sm += xs[n][c];
        xsum_out[(size_t)b * 688 + c] = sm * sig;
    }
}

// ---------------------------------------------------------------------------
extern "C" void kernel_launch(void* const* d_in, const int* in_sizes, int n_in,
                              void* d_out, int out_size, void* d_ws, size_t ws_size,
                              hipStream_t stream)
{
    const float* f_obj = (const float*)d_in[0];
    const float* bbox  = (const float*)d_in[1];
    const float* word  = (const float*)d_in[2];
    const float* sent  = (const float*)d_in[3];
    const float* body  = (const float*)d_in[4];
    const float* W1_o  = (const float*)d_in[5];
    const float* g_o = (const float*)d_in[6],  *b_o = (const float*)d_in[7];
    const float* m_o = (const float*)d_in[8],  *v_o = (const float*)d_in[9];
    const float* W2_o  = (const float*)d_in[10];
    const float* W1_s  = (const float*)d_in[11];
    const float* g_s = (const float*)d_in[12], *b_s = (const float*)d_in[13];
    const float* m_s = (const float*)d_in[14], *v_s = (const float*)d_in[15];
    const float* W2_s  = (const float*)d_in[16];
    const float* W1_b  = (const float*)d_in[17];
    const float* g_b = (const float*)d_in[18], *b_b = (const float*)d_in[19];
    const float* m_b = (const float*)d_in[20], *v_b = (const float*)d_in[21];
    const float* W2_b  = (const float*)d_in[22];
    const float* Wc1 = (const float*)d_in[23];
    const float* Wc2 = (const float*)d_in[24];
    const float* Wsa = (const float*)d_in[25];
    const float* Wf  = (const float*)d_in[26];
    const float* bf  = (const float*)d_in[27];
    const float* g_f = (const float*)d_in[28], *b_f = (const float*)d_in[29];
    const float* m_f = (const float*)d_in[30], *v_f = (const float*)d_in[31];
    float* out = (float*)d_out;

    // ---- workspace carve; total ~44.8 MB ----
    char* p = (char*)d_ws;
    unsigned short* w1s = (unsigned short*)p; p += 4194304;   // 512*4096
    unsigned short* w2s = (unsigned short*)p; p += 131072;    // 128*512
    unsigned short* w1o = (unsigned short*)p; p += 262144;    // 128*1024
    unsigned short* w2o = (unsigned short*)p; p += 32768;     // 128*128
    unsigned short* w1b = (unsigned short*)p; p += 1048576;   // 256*2048
    unsigned short* w2b = (unsigned short*)p; p += 65536;     // 128*256
    unsigned short* wfp = (unsigned short*)p; p += 360448;    // 256*704 padded
    unsigned short* h_s = (unsigned short*)p; p += 10485760;  // 10240*512
    unsigned short* h_o = (unsigned short*)p; p += 2621440;   // 10240*128
    unsigned short* h_b = (unsigned short*)p; p += 524288;    // 1024*256
    // split-K fp32 partial region; later aliased by stage-2/attn outputs.
    // bn_finalize zeroes it after reading, so stage-2's atomic accumulators
    // (sen_f/obj_f/bod_f, all inside the ps span) start from 0.
    char* region = p; p += 27262976;                          // 26 MB
    float* ps = (float*)region;                               // 10240*512 f32
    float* po = (float*)(region + 20971520);                  // 10240*128 f32
    float* pb = (float*)(region + 26214400);                  // 1024*256 f32
    float* sen_f  = (float*)region;                           // 10240*128 f32
    float* obj_f  = (float*)(region + 5242880);               // 10240*128 f32
    float* bod_f  = (float*)(region + 10485760);              // 1024*128 f32
    float* xsum_f = (float*)(region + 11010048);              // 1024*688 f32
    if ((size_t)(p - (char*)d_ws) > ws_size) return;

    // ---- 1) weights -> bf16 + zero split-K accumulators, one launch ----
    WArgs wa;
    wa.s[0] = { W1_s, w1s, 4096, 4096 };
    wa.s[1] = { W2_s, w2s,  512,  512 };
    wa.s[2] = { W1_o, w1o, 1024, 1024 };
    wa.s[3] = { W2_o, w2o,  128,  128 };
    wa.s[4] = { W1_b, w1b, 2048, 2048 };
    wa.s[5] = { W2_b, w2b,  256,  256 };
    wa.s[6] = { Wf,   wfp,  688,  704 };
    const int wn[7] = { 512*4096, 128*512, 128*1024, 128*128, 256*2048, 128*256, 256*704 };
    wa.off[0] = 0;
    for (int i = 0; i < 7; ++i) wa.off[i + 1] = wa.off[i] + wn[i];
    wa.zdst = (float4*)region;
    wa.zn   = 27262976 / 16;
    cvt_weights<<<(wa.off[7] + wa.zn + 255) / 256, 256, 0, stream>>>(wa);

    // ---- 2) stage-1 grouped GEMM, split-K (fp32 partials via atomicAdd)
    //      grid: sent 2*320 + obj 4*80 + body 4*16 = 1024 blocks (4/CU) ----
    {
        GArgs ga; ga.n = 3;
        ga.g[0] = { sent,  nullptr, w1s, ps, nullptr, nullptr, nullptr, nullptr, nullptr, nullptr,
                    10240, 512, 4096, 4096, 0, 4, 0,   320, 2 };
        ga.g[1] = { f_obj, nullptr, w1o, po, nullptr, nullptr, nullptr, nullptr, nullptr, nullptr,
                    10240, 128, 1024, 1024, 0, 1, 640, 80,  4 };
        ga.g[2] = { body,  nullptr, w1b, pb, nullptr, nullptr, nullptr, nullptr, nullptr, nullptr,
                    1024,  256, 2048, 2048, 0, 2, 960, 16,  4 };
        gemm_grouped<<<1024, 256, 0, stream>>>(ga);
    }

    // ---- 2b) BN + ReLU + bf16 convert of partial sums -> h_s/h_o/h_b;
    //      also zeroes ps/po/pb so stage-2 can atomically accumulate ----
    {
        FArgs fa;
        fa.s[0] = { ps, h_s, nullptr, nullptr, g_s, b_s, m_s, v_s, 512 };
        fa.s[1] = { po, h_o, nullptr, nullptr, g_o, b_o, m_o, v_o, 128 };
        fa.s[2] = { pb, h_b, nullptr, nullptr, g_b, b_b, m_b, v_b, 256 };
        fa.off[0] = 0;
        fa.off[1] = 10240 * 512 / 4;
        fa.off[2] = fa.off[1] + 10240 * 128 / 4;
        fa.off[3] = fa.off[2] + 1024 * 256 / 4;
        bn_finalize<<<(fa.off[3] + 255) / 256, 256, 0, stream>>>(fa);
    }

    // ---- 3) stage-2 grouped GEMM, split-K x2, atomic fp32 outputs ----
    {
        GArgs ga; ga.n = 3;
        ga.g[0] = { nullptr, h_s, w2s, sen_f, nullptr, nullptr, nullptr, nullptr, nullptr, nullptr,
                    10240, 128, 512, 512, 0, 1, 0,   80, 2 };
        ga.g[1] = { nullptr, h_o, w2o, obj_f, nullptr, nullptr, nullptr, nullptr, nullptr, nullptr,
                    10240, 128, 128, 128, 0, 1, 160, 80, 2 };
        ga.g[2] = { nullptr, h_b, w2b, bod_f, nullptr, nullptr, nullptr, nullptr, nullptr, nullptr,
                    1024,  128, 256, 256, 0, 1, 320, 8,  2 };
        gemm_grouped<<<336, 256, 0, stream>>>(ga);
    }

    // ---- 4) fused attention + sum over N ----
    attn_kernel<<<1024, 256, 0, stream>>>(obj_f, bbox, word, sen_f, bod_f,
                                          Wc1, Wc2, Wsa, xsum_f);

    // ---- 5) fc1 (+bias, BN, ReLU), K=688 zero-padded to 704 in staging ----
    {
        GArgs ga; ga.n = 1;
        ga.g[0] = { xsum_f, nullptr, wfp, out, nullptr, bf, g_f, b_f, m_f, v_f,
                    1024, 256, 704, 688, 1, 2, 0, 16, 1 };
        gemm_grouped<<<16, 256, 0, stream>>>(ga);
    }
}

// Round 6
// 522.442 us; speedup vs baseline: 1.0661x; 1.0661x over previous
//
#include <hip/hip_runtime.h>
#include <hip/hip_bf16.h>
#include <math.h>

typedef __attribute__((ext_vector_type(8))) short short8;   // 8 x bf16 (4 VGPRs)
typedef __attribute__((ext_vector_type(4))) float floatx4;  // MFMA C/D frag

static __device__ __forceinline__ unsigned short f2bf(float f) {
    unsigned int u = __float_as_uint(f);
    unsigned int r = (u + 0x7fffu + ((u >> 16) & 1u)) >> 16;   // RNE
    return (unsigned short)r;
}

// packed fp32x2 -> bf16x2 (RNE), single VALU inst (no builtin on gfx950)
static __device__ __forceinline__ unsigned int pk_bf16(float lo, float hi) {
    unsigned int r;
    asm("v_cvt_pk_bf16_f32 %0, %1, %2" : "=v"(r) : "v"(lo), "v"(hi));
    return r;
}

// async 16B global -> LDS copy (lds dest = wave-uniform base + lane*16)
static __device__ __forceinline__ void g2l16(const void* g, void* l) {
    __builtin_amdgcn_global_load_lds(
        (const __attribute__((address_space(1))) unsigned int*)g,
        (__attribute__((address_space(3))) unsigned int*)l,
        16, 0, 0);
}

// ---------------------------------------------------------------------------
// Grouped bf16 MFMA GEMM, double-buffered, optional split-K.
//   C[M,N] = A[M,K] @ W[N,K]^T
// A either fp32 (staged RAW into LDS via g2l16; converted to bf16 with
// v_cvt_pk_bf16_f32 during fragment load -- fully async staging, no register
// round-trip) or bf16 (g2l16 path). W always bf16 (pre-converted).
// K-pad support relies on W being zero-padded: A garbage columns multiply
// W zeros (A reads must merely not fault; xsum_f sits inside a large region).
// ksplit==1: epilogue applies optional bias + BN + ReLU, writes fp32/bf16.
// ksplit>1 : each k-chunk block atomicAdds its fp32 partial into Cf
//            (Cf pre-zeroed by prep kernel); BN/bias done by bn_finalize.
// Tiles: 128x128, 4 waves, each wave a 64x64 quadrant of 16x16x32 MFMAs.
// XCD-chunked blockid swizzle per group (nbb*ksplit must be mult of 8, and
// each group's block0 mult of 8) so column-blocks sharing an A-panel land on
// the same XCD's L2.
// ---------------------------------------------------------------------------
struct GDesc {
    const float*          Af;    // fp32 A (or null)
    const unsigned short* Ab;    // bf16 A (or null)
    const unsigned short* W;     // bf16 W, row stride = K
    float*          Cf;          // fp32 out / partial accum (or null)
    unsigned short* Cb;          // bf16 out (or null)
    const float *bias, *g, *b, *m, *v;
    int M, N, K;                 // K = padded to mult of 32 (W stride)
    int Kreal;                   // A row stride (= K unless padded)
    int fuse;                    // 1: BN+ReLU (ksplit==1 only)
    int nbx;                     // N / 128
    int block0;                  // first flat block id of this group
    int nbb;                     // blocks per k-chunk = nbx * (M/128)
    int ksplit;                  // #k-chunks (1 = no split)
};
struct GArgs { GDesc g[3]; int n; };

__global__ __launch_bounds__(256)
void gemm_grouped(GArgs ga)
{
    // fp32 A tiles: 2 x 16 KB; bf16-A path aliases the first 16 KB
    __shared__ float          As_f[2][4096];
    __shared__ unsigned short Bs[2][4096];   // 2 x 8 KB
    unsigned short* As_b = (unsigned short*)&As_f[0][0];  // [2][4096] ushorts

    const int bid = blockIdx.x;
    int gi = 0;
    #pragma unroll
    for (int i = 1; i < 3; ++i)
        if (i < ga.n && bid >= ga.g[i].block0) gi = i;
    const GDesc d = ga.g[gi];

    int local = bid - d.block0;
    // XCD-chunked swizzle: consecutive work items land on one XCD
    {
        const int cpx = (d.nbb * d.ksplit) >> 3;
        local = (local & 7) * cpx + (local >> 3);
    }
    int kc = 0;
    int Kc = d.K;
    if (d.ksplit > 1) {
        Kc = d.K / d.ksplit;
        kc = local / d.nbb;
        local -= kc * d.nbb;
    }
    const int kbeg = kc * Kc;
    const int bx = local % d.nbx;
    const int by = local / d.nbx;
    const int row0 = by * 128;
    const int col0 = bx * 128;

    const int tid  = threadIdx.x;
    const int wave = tid >> 6;
    const int lane = tid & 63;
    const int qd   = lane >> 4;
    const int ln   = lane & 15;
    const int wr   = (wave >> 1) * 64;
    const int wc   = (wave & 1) * 64;

    // bf16 g2l16 chunk mapping: chunk c -> row c>>2, k-offset (c&3)*8
    const int c0 = wave * 128 + lane;
    const int c1 = c0 + 64;
    const int r0 = c0 >> 2, k0 = (c0 & 3) * 8;
    const int r1 = c1 >> 2, k1 = (c1 & 3) * 8;

    // fp32-A g2l16 mapping: g2l16 #(wave*4+t): lane -> row wave*32+t*8+(l>>3),
    // col (l&7)*4 floats; LDS dest (wave*4+t)*1024 bytes + lane*16
    const int aro  = wave * 32 + (lane >> 3);  // + t*8
    const int acol = (lane & 7) * 4;

    const bool afp = (d.Af != nullptr);
    const int niter = Kc >> 5;

    floatx4 acc[4][4];
    #pragma unroll
    for (int i = 0; i < 4; ++i)
        #pragma unroll
        for (int j = 0; j < 4; ++j) acc[i][j] = (floatx4){0.f, 0.f, 0.f, 0.f};

    // ---- prologue: stage tile 0 into buffer 0 ----
    g2l16(d.W + (size_t)(col0 + r0) * d.K + kbeg + k0, &Bs[0][(size_t)wave * 1024]);
    g2l16(d.W + (size_t)(col0 + r1) * d.K + kbeg + k1, &Bs[0][(size_t)wave * 1024 + 512]);
    if (afp) {
        #pragma unroll
        for (int t = 0; t < 4; ++t)
            g2l16(d.Af + (size_t)(row0 + aro + t * 8) * d.Kreal + kbeg + acol,
                  &As_f[0][(size_t)(wave * 4 + t) * 256]);
    } else {
        g2l16(d.Ab + (size_t)(row0 + r0) * d.K + kbeg + k0, As_b + (size_t)wave * 1024);
        g2l16(d.Ab + (size_t)(row0 + r1) * d.K + kbeg + k1, As_b + (size_t)wave * 1024 + 512);
    }
    __syncthreads();

    int cur = 0;
    for (int it = 0; it < niter; ++it) {
        const int nxt = cur ^ 1;
        const bool pf = (it + 1 < niter);

        if (pf) {
            const int kg = kbeg + (it + 1) * 32;
            g2l16(d.W + (size_t)(col0 + r0) * d.K + kg + k0, &Bs[nxt][(size_t)wave * 1024]);
            g2l16(d.W + (size_t)(col0 + r1) * d.K + kg + k1, &Bs[nxt][(size_t)wave * 1024 + 512]);
            if (afp) {
                #pragma unroll
                for (int t = 0; t < 4; ++t)
                    g2l16(d.Af + (size_t)(row0 + aro + t * 8) * d.Kreal + kg + acol,
                          &As_f[nxt][(size_t)(wave * 4 + t) * 256]);
            } else {
                g2l16(d.Ab + (size_t)(row0 + r0) * d.K + kg + k0, As_b + (size_t)nxt * 4096 + wave * 1024);
                g2l16(d.Ab + (size_t)(row0 + r1) * d.K + kg + k1, As_b + (size_t)nxt * 4096 + wave * 1024 + 512);
            }
        }

        // ---- compute on current buffer ----
        short8 a[4], b[4];
        if (afp) {
            #pragma unroll
            for (int i = 0; i < 4; ++i) {
                const float* ap = &As_f[cur][(wr + i * 16 + ln) * 32 + qd * 8];
                float4 v0 = *(const float4*)ap;
                float4 v1 = *(const float4*)(ap + 4);
                int4 pk = { (int)pk_bf16(v0.x, v0.y), (int)pk_bf16(v0.z, v0.w),
                            (int)pk_bf16(v1.x, v1.y), (int)pk_bf16(v1.z, v1.w) };
                a[i] = *(short8*)&pk;
            }
        } else {
            #pragma unroll
            for (int i = 0; i < 4; ++i)
                a[i] = *(const short8*)&As_b[(size_t)cur * 4096 + (wr + i * 16 + ln) * 32 + qd * 8];
        }
        #pragma unroll
        for (int j = 0; j < 4; ++j)
            b[j] = *(const short8*)&Bs[cur][(wc + j * 16 + ln) * 32 + qd * 8];
        #pragma unroll
        for (int i = 0; i < 4; ++i)
            #pragma unroll
            for (int j = 0; j < 4; ++j)
                acc[i][j] = __builtin_amdgcn_mfma_f32_16x16x32_bf16(
                                a[i], b[j], acc[i][j], 0, 0, 0);

        __syncthreads();
        cur = nxt;
    }

    // ---- epilogue: C/D layout col = lane&15, row = quad*4 + reg ----
    if (d.ksplit > 1) {
        // fp32 partial accumulation; BN/bias deferred to bn_finalize
        #pragma unroll
        for (int j = 0; j < 4; ++j) {
            const int col = col0 + wc + j * 16 + ln;
            #pragma unroll
            for (int i = 0; i < 4; ++i) {
                #pragma unroll
                for (int r = 0; r < 4; ++r) {
                    const int row = row0 + wr + i * 16 + qd * 4 + r;
                    atomicAdd(&d.Cf[(size_t)row * d.N + col], acc[i][j][r]);
                }
            }
        }
        return;
    }

    #pragma unroll
    for (int j = 0; j < 4; ++j) {
        const int col = col0 + wc + j * 16 + ln;
        float add = d.bias ? d.bias[col] : 0.f;
        float scale = 1.f, shift = 0.f;
        if (d.fuse) {
            scale = d.g[col] * rsqrtf(d.v[col] + 1e-5f);
            shift = d.b[col] - d.m[col] * scale;
        }
        #pragma unroll
        for (int i = 0; i < 4; ++i) {
            #pragma unroll
            for (int r = 0; r < 4; ++r) {
                const int row = row0 + wr + i * 16 + qd * 4 + r;
                float vv = acc[i][j][r] + add;
                if (d.fuse) vv = fmaxf(vv * scale + shift, 0.f);
                if (d.Cf) d.Cf[(size_t)row * d.N + col] = vv;
                if (d.Cb) d.Cb[(size_t)row * d.N + col] = f2bf(vv);
            }
        }
    }
}

// ---------------------------------------------------------------------------
// Prep: all 7 weight matrices fp32 -> bf16 (fc padded) + zero-fill the
// split-K partial-accumulator region (replaces hipMemsetAsync dispatch)
// ---------------------------------------------------------------------------
struct WSeg { const float* src; unsigned short* dst; int Kreal; int Kp; };
struct WArgs { WSeg s[7]; int off[8]; float4* zdst; int zn; };

__global__ __launch_bounds__(256)
void cvt_weights(WArgs wa)
{
    int i = blockIdx.x * 256 + threadIdx.x;
    if (i >= wa.off[7]) {
        int z = i - wa.off[7];
        if (z < wa.zn) wa.zdst[z] = (float4){0.f, 0.f, 0.f, 0.f};
        return;
    }
    int s = 0;
    #pragma unroll
    for (int j = 1; j < 7; ++j) if (i >= wa.off[j]) s = j;
    const WSeg sg = wa.s[s];
    const int li = i - wa.off[s];
    const int r = li / sg.Kp, c = li - r * sg.Kp;
    sg.dst[li] = (c < sg.Kreal) ? f2bf(sg.src[(size_t)r * sg.Kreal + c])
                                : (unsigned short)0;
}

// ---------------------------------------------------------------------------
// BN + ReLU over split-K fp32 partial sums (vec4 per thread);
// writes bf16 (dstb) and/or fp32 (dstf)
// ---------------------------------------------------------------------------
struct FSeg { const float* src; unsigned short* dstb; float* dstf;
              const float *bias, *g, *b, *m, *v; int N; };
struct FArgs { FSeg s[3]; int off[4]; };   // offsets in vec4 units

__global__ __launch_bounds__(256)
void bn_finalize(FArgs fa)
{
    int i = blockIdx.x * 256 + threadIdx.x;
    if (i >= fa.off[3]) return;
    int s = 0;
    #pragma unroll
    for (int j = 1; j < 3; ++j) if (i >= fa.off[j]) s = j;
    const FSeg sg = fa.s[s];
    const int li = i - fa.off[s];
    const int e = li * 4;
    const int col = e % sg.N;              // N % 4 == 0 -> cols col..col+3
    float4 vv = *(const float4*)(sg.src + e);
    float4 fo;
    ushort4 o;
    #pragma unroll
    for (int r = 0; r < 4; ++r) {
        float x = (&vv.x)[r];
        if (sg.bias) x += sg.bias[col + r];
        float sc = sg.g[col + r] * rsqrtf(sg.v[col + r] + 1e-5f);
        float sh = sg.b[col + r] - sg.m[col + r] * sc;
        x = fmaxf(x * sc + sh, 0.f);
        (&fo.x)[r] = x;
        ((unsigned short*)&o)[r] = f2bf(x);
    }
    if (sg.dstb) *(ushort4*)(sg.dstb + e) = o;
    if (sg.dstf) *(float4*)(sg.dstf + e) = fo;
}

// ---------------------------------------------------------------------------
// Fused attention (per batch row): channel attn (N=10) + spatial conv k=7 +
// weighted sum over N -> xsum[b][688]
// ---------------------------------------------------------------------------
__global__ __launch_bounds__(256)
void attn_kernel(const float* __restrict__ obj, const float* __restrict__ bbox,
                 const float* __restrict__ word, const float* __restrict__ sen,
                 const float* __restrict__ bod,
                 const float* __restrict__ Wc1, const float* __restrict__ Wc2,
                 const float* __restrict__ Wsa,
                 float* __restrict__ xsum_out)
{
    const int b = blockIdx.x;
    const int tid = threadIdx.x;

    __shared__ float xs[10][688];
    __shared__ float s0[688], s1[688];
    __shared__ float avec[10], mvec[10], att[10];
    __shared__ float cw[14], c1[50], c2[50];

    if (tid < 14) cw[tid] = Wsa[tid];
    if (tid < 50) { c1[tid] = Wc1[tid]; c2[tid] = Wc2[tid]; }

    for (int n = 0; n < 10; ++n) {
        const float* o  = obj  + ((size_t)b * 10 + n) * 128;
        const float* bx = bbox + ((size_t)b * 10 + n) * 4;
        const float* w  = word + ((size_t)b * 10 + n) * 300;
        const float* s  = sen  + ((size_t)b * 10 + n) * 128;
        const float* bo = bod  + (size_t)b * 128;
        for (int c = tid; c < 688; c += 256) {
            float v;
            if      (c < 128) v = o[c];
            else if (c < 132) v = bx[c - 128];
            else if (c < 432) v = w[c - 132];
            else if (c < 560) v = s[c - 432];
            else              v = bo[c - 560];
            xs[n][c] = v;
        }
    }
    __syncthreads();

    // wave-parallel per-row mean/max: wave w handles rows w, w+4, w+8
    {
        const int wv = tid >> 6, ln2 = tid & 63;
        for (int n = wv; n < 10; n += 4) {
            float sm = 0.f, mx = -INFINITY;
            for (int c = ln2; c < 688; c += 64) {
                float v = xs[n][c];
                sm += v; mx = fmaxf(mx, v);
            }
            #pragma unroll
            for (int off = 32; off > 0; off >>= 1) {
                sm += __shfl_down(sm, off);
                mx = fmaxf(mx, __shfl_down(mx, off));
            }
            if (ln2 == 0) { avec[n] = sm * (1.f / 688.f); mvec[n] = mx; }
        }
    }
    __syncthreads();

    if (tid == 0) {
        float ha[5], hm[5];
        #pragma unroll
        for (int i = 0; i < 5; ++i) {
            float sa_ = 0.f, sm_ = 0.f;
            #pragma unroll
            for (int j = 0; j < 10; ++j) {
                sa_ += c1[i * 10 + j] * avec[j];
                sm_ += c1[i * 10 + j] * mvec[j];
            }
            ha[i] = fmaxf(sa_, 0.f);
            hm[i] = fmaxf(sm_, 0.f);
        }
        #pragma unroll
        for (int j = 0; j < 10; ++j) {
            float v = 0.f;
            #pragma unroll
            for (int i = 0; i < 5; ++i) v += c2[j * 5 + i] * (ha[i] + hm[i]);
            att[j] = 1.f / (1.f + expf(-v));
        }
    }
    __syncthreads();

    for (int c = tid; c < 688; c += 256) {
        float sm = 0.f, mx = -INFINITY;
        #pragma unroll
        for (int n = 0; n < 10; ++n) {
            float v = xs[n][c] * att[n];
            xs[n][c] = v;
            sm += v; mx = fmaxf(mx, v);
        }
        s0[c] = sm * 0.1f;
        s1[c] = mx;
    }
    __syncthreads();

    for (int c = tid; c < 688; c += 256) {
        float sa = 0.f;
        #pragma unroll
        for (int j = 0; j < 7; ++j) {
            int cc = c + j - 3;
            if (cc >= 0 && cc < 688)
                sa += cw[j] * s0[cc] + cw[7 + j] * s1[cc];
        }
        float sig = 1.f / (1.f + expf(-sa));
        float sm = 0.f;
        #pragma unroll
        for (int n = 0; n < 10; ++n) sm += xs[n][c];
        xsum_out[(size_t)b * 688 + c] = sm * sig;
    }
}

// ---------------------------------------------------------------------------
extern "C" void kernel_launch(void* const* d_in, const int* in_sizes, int n_in,
                              void* d_out, int out_size, void* d_ws, size_t ws_size,
                              hipStream_t stream)
{
    const float* f_obj = (const float*)d_in[0];
    const float* bbox  = (const float*)d_in[1];
    const float* word  = (const float*)d_in[2];
    const float* sent  = (const float*)d_in[3];
    const float* body  = (const float*)d_in[4];
    const float* W1_o  = (const float*)d_in[5];
    const float* g_o = (const float*)d_in[6],  *b_o = (const float*)d_in[7];
    const float* m_o = (const float*)d_in[8],  *v_o = (const float*)d_in[9];
    const float* W2_o  = (const float*)d_in[10];
    const float* W1_s  = (const float*)d_in[11];
    const float* g_s = (const float*)d_in[12], *b_s = (const float*)d_in[13];
    const float* m_s = (const float*)d_in[14], *v_s = (const float*)d_in[15];
    const float* W2_s  = (const float*)d_in[16];
    const float* W1_b  = (const float*)d_in[17];
    const float* g_b = (const float*)d_in[18], *b_b = (const float*)d_in[19];
    const float* m_b = (const float*)d_in[20], *v_b = (const float*)d_in[21];
    const float* W2_b  = (const float*)d_in[22];
    const float* Wc1 = (const float*)d_in[23];
    const float* Wc2 = (const float*)d_in[24];
    const float* Wsa = (const float*)d_in[25];
    const float* Wf  = (const float*)d_in[26];
    const float* bf  = (const float*)d_in[27];
    const float* g_f = (const float*)d_in[28], *b_f = (const float*)d_in[29];
    const float* m_f = (const float*)d_in[30], *v_f = (const float*)d_in[31];
    float* out = (float*)d_out;

    // ---- workspace carve; total ~44.8 MB ----
    char* p = (char*)d_ws;
    unsigned short* w1s = (unsigned short*)p; p += 4194304;   // 512*4096
    unsigned short* w2s = (unsigned short*)p; p += 131072;    // 128*512
    unsigned short* w1o = (unsigned short*)p; p += 262144;    // 128*1024
    unsigned short* w2o = (unsigned short*)p; p += 32768;     // 128*128
    unsigned short* w1b = (unsigned short*)p; p += 1048576;   // 256*2048
    unsigned short* w2b = (unsigned short*)p; p += 65536;     // 128*256
    unsigned short* wfp = (unsigned short*)p; p += 360448;    // 256*704 padded
    unsigned short* h_s = (unsigned short*)p; p += 10485760;  // 10240*512
    unsigned short* h_o = (unsigned short*)p; p += 2621440;   // 10240*128
    unsigned short* h_b = (unsigned short*)p; p += 524288;    // 1024*256
    // split-K fp32 partial region; later aliased by stage-2/attn outputs
    // (partials are dead after bn_finalize, which runs before stage-2)
    char* region = p; p += 27262976;                          // 26 MB
    float* ps = (float*)region;                               // 10240*512 f32
    float* po = (float*)(region + 20971520);                  // 10240*128 f32
    float* pb = (float*)(region + 26214400);                  // 1024*256 f32
    float* sen_f  = (float*)region;                           // 10240*128 f32
    float* obj_f  = (float*)(region + 5242880);               // 10240*128 f32
    float* bod_f  = (float*)(region + 10485760);              // 1024*128 f32
    float* xsum_f = (float*)(region + 11010048);              // 1024*688 f32
    if ((size_t)(p - (char*)d_ws) > ws_size) return;

    // ---- 1) weights -> bf16 + zero split-K accumulators, one launch ----
    WArgs wa;
    wa.s[0] = { W1_s, w1s, 4096, 4096 };
    wa.s[1] = { W2_s, w2s,  512,  512 };
    wa.s[2] = { W1_o, w1o, 1024, 1024 };
    wa.s[3] = { W2_o, w2o,  128,  128 };
    wa.s[4] = { W1_b, w1b, 2048, 2048 };
    wa.s[5] = { W2_b, w2b,  256,  256 };
    wa.s[6] = { Wf,   wfp,  688,  704 };
    const int wn[7] = { 512*4096, 128*512, 128*1024, 128*128, 256*2048, 128*256, 256*704 };
    wa.off[0] = 0;
    for (int i = 0; i < 7; ++i) wa.off[i + 1] = wa.off[i] + wn[i];
    wa.zdst = (float4*)region;
    wa.zn   = 27262976 / 16;
    cvt_weights<<<(wa.off[7] + wa.zn + 255) / 256, 256, 0, stream>>>(wa);

    // ---- 2) stage-1 grouped GEMM, split-K x2, async fp32-A staging ----
    //      grid: sent 2*320 + obj 2*80 + body 2*16 = 832 blocks
    //      (all group sizes and block0 offsets are multiples of 8)
    {
        GArgs ga; ga.n = 3;
        ga.g[0] = { sent,  nullptr, w1s, ps, nullptr, nullptr, nullptr, nullptr, nullptr, nullptr,
                    10240, 512, 4096, 4096, 0, 4, 0,   320, 2 };
        ga.g[1] = { f_obj, nullptr, w1o, po, nullptr, nullptr, nullptr, nullptr, nullptr, nullptr,
                    10240, 128, 1024, 1024, 0, 1, 640, 80,  2 };
        ga.g[2] = { body,  nullptr, w1b, pb, nullptr, nullptr, nullptr, nullptr, nullptr, nullptr,
                    1024,  256, 2048, 2048, 0, 2, 800, 16,  2 };
        gemm_grouped<<<832, 256, 0, stream>>>(ga);
    }

    // ---- 2b) BN + ReLU + bf16 convert of partial sums -> h_s/h_o/h_b ----
    {
        FArgs fa;
        fa.s[0] = { ps, h_s, nullptr, nullptr, g_s, b_s, m_s, v_s, 512 };
        fa.s[1] = { po, h_o, nullptr, nullptr, g_o, b_o, m_o, v_o, 128 };
        fa.s[2] = { pb, h_b, nullptr, nullptr, g_b, b_b, m_b, v_b, 256 };
        fa.off[0] = 0;
        fa.off[1] = 10240 * 512 / 4;
        fa.off[2] = fa.off[1] + 10240 * 128 / 4;
        fa.off[3] = fa.off[2] + 1024 * 256 / 4;
        bn_finalize<<<(fa.off[3] + 255) / 256, 256, 0, stream>>>(fa);
    }

    // ---- 3) stage-2 grouped GEMM (bf16 A; fp32 out) ----
    {
        GArgs ga; ga.n = 3;
        ga.g[0] = { nullptr, h_s, w2s, sen_f, nullptr, nullptr, nullptr, nullptr, nullptr, nullptr,
                    10240, 128, 512, 512, 0, 1, 0,   80, 1 };
        ga.g[1] = { nullptr, h_o, w2o, obj_f, nullptr, nullptr, nullptr, nullptr, nullptr, nullptr,
                    10240, 128, 128, 128, 0, 1, 80,  80, 1 };
        ga.g[2] = { nullptr, h_b, w2b, bod_f, nullptr, nullptr, nullptr, nullptr, nullptr, nullptr,
                    1024,  128, 256, 256, 0, 1, 160, 8,  1 };
        gemm_grouped<<<168, 256, 0, stream>>>(ga);
    }

    // ---- 4) fused attention + sum over N ----
    attn_kernel<<<1024, 256, 0, stream>>>(obj_f, bbox, word, sen_f, bod_f,
                                          Wc1, Wc2, Wsa, xsum_f);

    // ---- 5) fc1 (+bias, BN, ReLU), K=688 zero-padded to 704 (W-pad only;
    //      A overreads past row end multiply W zeros -> contribute 0) ----
    {
        GArgs ga; ga.n = 1;
        ga.g[0] = { xsum_f, nullptr, wfp, out, nullptr, bf, g_f, b_f, m_f, v_f,
                    1024, 256, 704, 688, 1, 2, 0, 16, 1 };
        gemm_grouped<<<16, 256, 0, stream>>>(ga);
    }
}

// Round 7
// 512.541 us; speedup vs baseline: 1.0867x; 1.0193x over previous
//
#include <hip/hip_runtime.h>
#include <hip/hip_bf16.h>
#include <math.h>

typedef __attribute__((ext_vector_type(8))) short short8;   // 8 x bf16 (4 VGPRs)
typedef __attribute__((ext_vector_type(4))) float floatx4;  // MFMA C/D frag

static __device__ __forceinline__ unsigned short f2bf(float f) {
    unsigned int u = __float_as_uint(f);
    unsigned int r = (u + 0x7fffu + ((u >> 16) & 1u)) >> 16;   // RNE
    return (unsigned short)r;
}

// packed fp32x2 -> bf16x2 (RNE), single VALU inst (no builtin on gfx950)
static __device__ __forceinline__ unsigned int pk_bf16(float lo, float hi) {
    unsigned int r;
    asm("v_cvt_pk_bf16_f32 %0, %1, %2" : "=v"(r) : "v"(lo), "v"(hi));
    return r;
}

// async 16B global -> LDS copy (lds dest = wave-uniform base + lane*16)
static __device__ __forceinline__ void g2l16(const void* g, void* l) {
    __builtin_amdgcn_global_load_lds(
        (const __attribute__((address_space(1))) unsigned int*)g,
        (__attribute__((address_space(3))) unsigned int*)l,
        16, 0, 0);
}

// ---------------------------------------------------------------------------
// Grouped bf16 MFMA GEMM, double-buffered, optional split-K.
//   C[M,N] = A[M,K] @ W[N,K]^T
// A either fp32 (staged RAW into LDS via g2l16, XOR-swizzled; converted to
// bf16 with v_cvt_pk_bf16_f32 during fragment load) or bf16 (g2l16 path,
// XOR-swizzled). W always bf16 (pre-converted), XOR-swizzled.
//
// T2 bank-conflict swizzle (rule #21: swizzle source + read, LDS stays
// linear since global_load_lds writes base+lane*16):
//   fp32 tile [128 rows][8 x 16B slots]: LDS[r][s] = global[r][s ^ (r&7)]
//     (source slot for g2l16 lane l: (l&7) ^ (l>>3); read slot: g ^ (r&7))
//   bf16 tile [128 rows][4 x 16B slots]: LDS[r][s] = global[r][s ^ ((r>>1)&3)]
//     (source slot for chunk c: (c&3) ^ ((c>>3)&3); read slot: g ^ ((r>>1)&3))
//
// ksplit==1: epilogue applies optional bias + BN + ReLU, writes fp32/bf16.
// ksplit>1 : each k-chunk block atomicAdds its fp32 partial into Cf
//            (Cf pre-zeroed by prep kernel); BN/bias done by bn_finalize.
// Tiles: 128x128, 4 waves, each wave a 64x64 quadrant of 16x16x32 MFMAs.
// XCD-chunked blockid swizzle per group (group sizes & block0 mult of 8).
// ---------------------------------------------------------------------------
struct GDesc {
    const float*          Af;    // fp32 A (or null)
    const unsigned short* Ab;    // bf16 A (or null)
    const unsigned short* W;     // bf16 W, row stride = K
    float*          Cf;          // fp32 out / partial accum (or null)
    unsigned short* Cb;          // bf16 out (or null)
    const float *bias, *g, *b, *m, *v;
    int M, N, K;                 // K = padded to mult of 32 (W stride)
    int Kreal;                   // A row stride (= K unless padded)
    int fuse;                    // 1: BN+ReLU (ksplit==1 only)
    int nbx;                     // N / 128
    int block0;                  // first flat block id of this group
    int nbb;                     // blocks per k-chunk = nbx * (M/128)
    int ksplit;                  // #k-chunks (1 = no split)
};
struct GArgs { GDesc g[3]; int n; };

__global__ __launch_bounds__(256)
void gemm_grouped(GArgs ga)
{
    // fp32 A tiles: 2 x 16 KB; bf16-A path aliases the first 16 KB
    __shared__ float          As_f[2][4096];
    __shared__ unsigned short Bs[2][4096];   // 2 x 8 KB
    unsigned short* As_b = (unsigned short*)&As_f[0][0];  // [2][4096] ushorts

    const int bid = blockIdx.x;
    int gi = 0;
    #pragma unroll
    for (int i = 1; i < 3; ++i)
        if (i < ga.n && bid >= ga.g[i].block0) gi = i;
    const GDesc d = ga.g[gi];

    int local = bid - d.block0;
    // XCD-chunked swizzle: consecutive work items land on one XCD
    {
        const int cpx = (d.nbb * d.ksplit) >> 3;
        local = (local & 7) * cpx + (local >> 3);
    }
    int kc = 0;
    int Kc = d.K;
    if (d.ksplit > 1) {
        Kc = d.K / d.ksplit;
        kc = local / d.nbb;
        local -= kc * d.nbb;
    }
    const int kbeg = kc * Kc;
    const int bx = local % d.nbx;
    const int by = local / d.nbx;
    const int row0 = by * 128;
    const int col0 = bx * 128;

    const int tid  = threadIdx.x;
    const int wave = tid >> 6;
    const int lane = tid & 63;
    const int qd   = lane >> 4;
    const int ln   = lane & 15;
    const int wr   = (wave >> 1) * 64;
    const int wc   = (wave & 1) * 64;

    // bf16 g2l16 chunk mapping: chunk c -> row c>>2, source 16B-slot
    // (c&3)^((c>>3)&3) -> k-offset in ushorts = slot*8
    const int c0 = wave * 128 + lane;
    const int c1 = c0 + 64;
    const int r0 = c0 >> 2, k0 = (((c0 & 3) ^ ((c0 >> 3) & 3))) * 8;
    const int r1 = c1 >> 2, k1 = (((c1 & 3) ^ ((c1 >> 3) & 3))) * 8;

    // fp32-A g2l16 mapping: g2l16 #(wave*4+t): lane -> row wave*32+t*8+(l>>3),
    // source float col = ((l&7) ^ (l>>3)) * 4; LDS dest linear
    const int aro  = wave * 32 + (lane >> 3);  // + t*8
    const int acol = ((lane & 7) ^ (lane >> 3)) * 4;

    const bool afp = (d.Af != nullptr);
    const int niter = Kc >> 5;

    floatx4 acc[4][4];
    #pragma unroll
    for (int i = 0; i < 4; ++i)
        #pragma unroll
        for (int j = 0; j < 4; ++j) acc[i][j] = (floatx4){0.f, 0.f, 0.f, 0.f};

    // ---- prologue: stage tile 0 into buffer 0 ----
    g2l16(d.W + (size_t)(col0 + r0) * d.K + kbeg + k0, &Bs[0][(size_t)wave * 1024]);
    g2l16(d.W + (size_t)(col0 + r1) * d.K + kbeg + k1, &Bs[0][(size_t)wave * 1024 + 512]);
    if (afp) {
        #pragma unroll
        for (int t = 0; t < 4; ++t)
            g2l16(d.Af + (size_t)(row0 + aro + t * 8) * d.Kreal + kbeg + acol,
                  &As_f[0][(size_t)(wave * 4 + t) * 256]);
    } else {
        g2l16(d.Ab + (size_t)(row0 + r0) * d.K + kbeg + k0, As_b + (size_t)wave * 1024);
        g2l16(d.Ab + (size_t)(row0 + r1) * d.K + kbeg + k1, As_b + (size_t)wave * 1024 + 512);
    }
    __syncthreads();

    int cur = 0;
    for (int it = 0; it < niter; ++it) {
        const int nxt = cur ^ 1;
        const bool pf = (it + 1 < niter);

        if (pf) {
            const int kg = kbeg + (it + 1) * 32;
            g2l16(d.W + (size_t)(col0 + r0) * d.K + kg + k0, &Bs[nxt][(size_t)wave * 1024]);
            g2l16(d.W + (size_t)(col0 + r1) * d.K + kg + k1, &Bs[nxt][(size_t)wave * 1024 + 512]);
            if (afp) {
                #pragma unroll
                for (int t = 0; t < 4; ++t)
                    g2l16(d.Af + (size_t)(row0 + aro + t * 8) * d.Kreal + kg + acol,
                          &As_f[nxt][(size_t)(wave * 4 + t) * 256]);
            } else {
                g2l16(d.Ab + (size_t)(row0 + r0) * d.K + kg + k0, As_b + (size_t)nxt * 4096 + wave * 1024);
                g2l16(d.Ab + (size_t)(row0 + r1) * d.K + kg + k1, As_b + (size_t)nxt * 4096 + wave * 1024 + 512);
            }
        }

        // ---- compute on current buffer (swizzled reads) ----
        short8 a[4], b[4];
        if (afp) {
            #pragma unroll
            for (int i = 0; i < 4; ++i) {
                const int row = wr + i * 16 + ln;
                const int sw  = row & 7;
                float4 v0 = *(const float4*)&As_f[cur][row * 32 + ((qd * 2)     ^ sw) * 4];
                float4 v1 = *(const float4*)&As_f[cur][row * 32 + ((qd * 2 + 1) ^ sw) * 4];
                int4 pk = { (int)pk_bf16(v0.x, v0.y), (int)pk_bf16(v0.z, v0.w),
                            (int)pk_bf16(v1.x, v1.y), (int)pk_bf16(v1.z, v1.w) };
                a[i] = *(short8*)&pk;
            }
        } else {
            #pragma unroll
            for (int i = 0; i < 4; ++i) {
                const int row = wr + i * 16 + ln;
                const int sw  = (row >> 1) & 3;
                a[i] = *(const short8*)&As_b[(size_t)cur * 4096 + row * 32 + (qd ^ sw) * 8];
            }
        }
        #pragma unroll
        for (int j = 0; j < 4; ++j) {
            const int row = wc + j * 16 + ln;
            const int sw  = (row >> 1) & 3;
            b[j] = *(const short8*)&Bs[cur][row * 32 + (qd ^ sw) * 8];
        }
        #pragma unroll
        for (int i = 0; i < 4; ++i)
            #pragma unroll
            for (int j = 0; j < 4; ++j)
                acc[i][j] = __builtin_amdgcn_mfma_f32_16x16x32_bf16(
                                a[i], b[j], acc[i][j], 0, 0, 0);

        __syncthreads();
        cur = nxt;
    }

    // ---- epilogue: C/D layout col = lane&15, row = quad*4 + reg ----
    if (d.ksplit > 1) {
        // fp32 partial accumulation; BN/bias deferred to bn_finalize
        #pragma unroll
        for (int j = 0; j < 4; ++j) {
            const int col = col0 + wc + j * 16 + ln;
            #pragma unroll
            for (int i = 0; i < 4; ++i) {
                #pragma unroll
                for (int r = 0; r < 4; ++r) {
                    const int row = row0 + wr + i * 16 + qd * 4 + r;
                    atomicAdd(&d.Cf[(size_t)row * d.N + col], acc[i][j][r]);
                }
            }
        }
        return;
    }

    #pragma unroll
    for (int j = 0; j < 4; ++j) {
        const int col = col0 + wc + j * 16 + ln;
        float add = d.bias ? d.bias[col] : 0.f;
        float scale = 1.f, shift = 0.f;
        if (d.fuse) {
            scale = d.g[col] * rsqrtf(d.v[col] + 1e-5f);
            shift = d.b[col] - d.m[col] * scale;
        }
        #pragma unroll
        for (int i = 0; i < 4; ++i) {
            #pragma unroll
            for (int r = 0; r < 4; ++r) {
                const int row = row0 + wr + i * 16 + qd * 4 + r;
                float vv = acc[i][j][r] + add;
                if (d.fuse) vv = fmaxf(vv * scale + shift, 0.f);
                if (d.Cf) d.Cf[(size_t)row * d.N + col] = vv;
                if (d.Cb) d.Cb[(size_t)row * d.N + col] = f2bf(vv);
            }
        }
    }
}

// ---------------------------------------------------------------------------
// Prep: all 7 weight matrices fp32 -> bf16 (fc padded) + zero-fill the
// split-K partial-accumulator region (replaces hipMemsetAsync dispatch)
// ---------------------------------------------------------------------------
struct WSeg { const float* src; unsigned short* dst; int Kreal; int Kp; };
struct WArgs { WSeg s[7]; int off[8]; float4* zdst; int zn; };

__global__ __launch_bounds__(256)
void cvt_weights(WArgs wa)
{
    int i = blockIdx.x * 256 + threadIdx.x;
    if (i >= wa.off[7]) {
        int z = i - wa.off[7];
        if (z < wa.zn) wa.zdst[z] = (float4){0.f, 0.f, 0.f, 0.f};
        return;
    }
    int s = 0;
    #pragma unroll
    for (int j = 1; j < 7; ++j) if (i >= wa.off[j]) s = j;
    const WSeg sg = wa.s[s];
    const int li = i - wa.off[s];
    const int r = li / sg.Kp, c = li - r * sg.Kp;
    sg.dst[li] = (c < sg.Kreal) ? f2bf(sg.src[(size_t)r * sg.Kreal + c])
                                : (unsigned short)0;
}

// ---------------------------------------------------------------------------
// BN + ReLU over split-K fp32 partial sums (vec4 per thread);
// writes bf16 (dstb) and/or fp32 (dstf)
// ---------------------------------------------------------------------------
struct FSeg { const float* src; unsigned short* dstb; float* dstf;
              const float *bias, *g, *b, *m, *v; int N; };
struct FArgs { FSeg s[3]; int off[4]; };   // offsets in vec4 units

__global__ __launch_bounds__(256)
void bn_finalize(FArgs fa)
{
    int i = blockIdx.x * 256 + threadIdx.x;
    if (i >= fa.off[3]) return;
    int s = 0;
    #pragma unroll
    for (int j = 1; j < 3; ++j) if (i >= fa.off[j]) s = j;
    const FSeg sg = fa.s[s];
    const int li = i - fa.off[s];
    const int e = li * 4;
    const int col = e % sg.N;              // N % 4 == 0 -> cols col..col+3
    float4 vv = *(const float4*)(sg.src + e);
    float4 fo;
    ushort4 o;
    #pragma unroll
    for (int r = 0; r < 4; ++r) {
        float x = (&vv.x)[r];
        if (sg.bias) x += sg.bias[col + r];
        float sc = sg.g[col + r] * rsqrtf(sg.v[col + r] + 1e-5f);
        float sh = sg.b[col + r] - sg.m[col + r] * sc;
        x = fmaxf(x * sc + sh, 0.f);
        (&fo.x)[r] = x;
        ((unsigned short*)&o)[r] = f2bf(x);
    }
    if (sg.dstb) *(ushort4*)(sg.dstb + e) = o;
    if (sg.dstf) *(float4*)(sg.dstf + e) = fo;
}

// ---------------------------------------------------------------------------
// Fused attention (per batch row): channel attn (N=10) + spatial conv k=7 +
// weighted sum over N -> xsum[b][688]
// ---------------------------------------------------------------------------
__global__ __launch_bounds__(256)
void attn_kernel(const float* __restrict__ obj, const float* __restrict__ bbox,
                 const float* __restrict__ word, const float* __restrict__ sen,
                 const float* __restrict__ bod,
                 const float* __restrict__ Wc1, const float* __restrict__ Wc2,
                 const float* __restrict__ Wsa,
                 float* __restrict__ xsum_out)
{
    const int b = blockIdx.x;
    const int tid = threadIdx.x;

    __shared__ float xs[10][688];
    __shared__ float s0[688], s1[688];
    __shared__ float avec[10], mvec[10], att[10];
    __shared__ float cw[14], c1[50], c2[50];

    if (tid < 14) cw[tid] = Wsa[tid];
    if (tid < 50) { c1[tid] = Wc1[tid]; c2[tid] = Wc2[tid]; }

    for (int n = 0; n < 10; ++n) {
        const float* o  = obj  + ((size_t)b * 10 + n) * 128;
        const float* bx = bbox + ((size_t)b * 10 + n) * 4;
        const float* w  = word + ((size_t)b * 10 + n) * 300;
        const float* s  = sen  + ((size_t)b * 10 + n) * 128;
        const float* bo = bod  + (size_t)b * 128;
        for (int c = tid; c < 688; c += 256) {
            float v;
            if      (c < 128) v = o[c];
            else if (c < 132) v = bx[c - 128];
            else if (c < 432) v = w[c - 132];
            else if (c < 560) v = s[c - 432];
            else              v = bo[c - 560];
            xs[n][c] = v;
        }
    }
    __syncthreads();

    // wave-parallel per-row mean/max: wave w handles rows w, w+4, w+8
    {
        const int wv = tid >> 6, ln2 = tid & 63;
        for (int n = wv; n < 10; n += 4) {
            float sm = 0.f, mx = -INFINITY;
            for (int c = ln2; c < 688; c += 64) {
                float v = xs[n][c];
                sm += v; mx = fmaxf(mx, v);
            }
            #pragma unroll
            for (int off = 32; off > 0; off >>= 1) {
                sm += __shfl_down(sm, off);
                mx = fmaxf(mx, __shfl_down(mx, off));
            }
            if (ln2 == 0) { avec[n] = sm * (1.f / 688.f); mvec[n] = mx; }
        }
    }
    __syncthreads();

    if (tid == 0) {
        float ha[5], hm[5];
        #pragma unroll
        for (int i = 0; i < 5; ++i) {
            float sa_ = 0.f, sm_ = 0.f;
            #pragma unroll
            for (int j = 0; j < 10; ++j) {
                sa_ += c1[i * 10 + j] * avec[j];
                sm_ += c1[i * 10 + j] * mvec[j];
            }
            ha[i] = fmaxf(sa_, 0.f);
            hm[i] = fmaxf(sm_, 0.f);
        }
        #pragma unroll
        for (int j = 0; j < 10; ++j) {
            float v = 0.f;
            #pragma unroll
            for (int i = 0; i < 5; ++i) v += c2[j * 5 + i] * (ha[i] + hm[i]);
            att[j] = 1.f / (1.f + expf(-v));
        }
    }
    __syncthreads();

    for (int c = tid; c < 688; c += 256) {
        float sm = 0.f, mx = -INFINITY;
        #pragma unroll
        for (int n = 0; n < 10; ++n) {
            float v = xs[n][c] * att[n];
            xs[n][c] = v;
            sm += v; mx = fmaxf(mx, v);
        }
        s0[c] = sm * 0.1f;
        s1[c] = mx;
    }
    __syncthreads();

    for (int c = tid; c < 688; c += 256) {
        float sa = 0.f;
        #pragma unroll
        for (int j = 0; j < 7; ++j) {
            int cc = c + j - 3;
            if (cc >= 0 && cc < 688)
                sa += cw[j] * s0[cc] + cw[7 + j] * s1[cc];
        }
        float sig = 1.f / (1.f + expf(-sa));
        float sm = 0.f;
        #pragma unroll
        for (int n = 0; n < 10; ++n) sm += xs[n][c];
        xsum_out[(size_t)b * 688 + c] = sm * sig;
    }
}

// ---------------------------------------------------------------------------
extern "C" void kernel_launch(void* const* d_in, const int* in_sizes, int n_in,
                              void* d_out, int out_size, void* d_ws, size_t ws_size,
                              hipStream_t stream)
{
    const float* f_obj = (const float*)d_in[0];
    const float* bbox  = (const float*)d_in[1];
    const float* word  = (const float*)d_in[2];
    const float* sent  = (const float*)d_in[3];
    const float* body  = (const float*)d_in[4];
    const float* W1_o  = (const float*)d_in[5];
    const float* g_o = (const float*)d_in[6],  *b_o = (const float*)d_in[7];
    const float* m_o = (const float*)d_in[8],  *v_o = (const float*)d_in[9];
    const float* W2_o  = (const float*)d_in[10];
    const float* W1_s  = (const float*)d_in[11];
    const float* g_s = (const float*)d_in[12], *b_s = (const float*)d_in[13];
    const float* m_s = (const float*)d_in[14], *v_s = (const float*)d_in[15];
    const float* W2_s  = (const float*)d_in[16];
    const float* W1_b  = (const float*)d_in[17];
    const float* g_b = (const float*)d_in[18], *b_b = (const float*)d_in[19];
    const float* m_b = (const float*)d_in[20], *v_b = (const float*)d_in[21];
    const float* W2_b  = (const float*)d_in[22];
    const float* Wc1 = (const float*)d_in[23];
    const float* Wc2 = (const float*)d_in[24];
    const float* Wsa = (const float*)d_in[25];
    const float* Wf  = (const float*)d_in[26];
    const float* bf  = (const float*)d_in[27];
    const float* g_f = (const float*)d_in[28], *b_f = (const float*)d_in[29];
    const float* m_f = (const float*)d_in[30], *v_f = (const float*)d_in[31];
    float* out = (float*)d_out;

    // ---- workspace carve; total ~44.8 MB ----
    char* p = (char*)d_ws;
    unsigned short* w1s = (unsigned short*)p; p += 4194304;   // 512*4096
    unsigned short* w2s = (unsigned short*)p; p += 131072;    // 128*512
    unsigned short* w1o = (unsigned short*)p; p += 262144;    // 128*1024
    unsigned short* w2o = (unsigned short*)p; p += 32768;     // 128*128
    unsigned short* w1b = (unsigned short*)p; p += 1048576;   // 256*2048
    unsigned short* w2b = (unsigned short*)p; p += 65536;     // 128*256
    unsigned short* wfp = (unsigned short*)p; p += 360448;    // 256*704 padded
    unsigned short* h_s = (unsigned short*)p; p += 10485760;  // 10240*512
    unsigned short* h_o = (unsigned short*)p; p += 2621440;   // 10240*128
    unsigned short* h_b = (unsigned short*)p; p += 524288;    // 1024*256
    // split-K fp32 partial region; later aliased by stage-2/attn outputs
    // (partials are dead after bn_finalize, which runs before stage-2)
    char* region = p; p += 27262976;                          // 26 MB
    float* ps = (float*)region;                               // 10240*512 f32
    float* po = (float*)(region + 20971520);                  // 10240*128 f32
    float* pb = (float*)(region + 26214400);                  // 1024*256 f32
    float* sen_f  = (float*)region;                           // 10240*128 f32
    float* obj_f  = (float*)(region + 5242880);               // 10240*128 f32
    float* bod_f  = (float*)(region + 10485760);              // 1024*128 f32
    float* xsum_f = (float*)(region + 11010048);              // 1024*688 f32
    if ((size_t)(p - (char*)d_ws) > ws_size) return;

    // ---- 1) weights -> bf16 + zero split-K accumulators, one launch ----
    WArgs wa;
    wa.s[0] = { W1_s, w1s, 4096, 4096 };
    wa.s[1] = { W2_s, w2s,  512,  512 };
    wa.s[2] = { W1_o, w1o, 1024, 1024 };
    wa.s[3] = { W2_o, w2o,  128,  128 };
    wa.s[4] = { W1_b, w1b, 2048, 2048 };
    wa.s[5] = { W2_b, w2b,  256,  256 };
    wa.s[6] = { Wf,   wfp,  688,  704 };
    const int wn[7] = { 512*4096, 128*512, 128*1024, 128*128, 256*2048, 128*256, 256*704 };
    wa.off[0] = 0;
    for (int i = 0; i < 7; ++i) wa.off[i + 1] = wa.off[i] + wn[i];
    wa.zdst = (float4*)region;
    wa.zn   = 27262976 / 16;
    cvt_weights<<<(wa.off[7] + wa.zn + 255) / 256, 256, 0, stream>>>(wa);

    // ---- 2) stage-1 grouped GEMM, split-K x2, async fp32-A staging ----
    //      grid: sent 2*320 + obj 2*80 + body 2*16 = 832 blocks
    //      (all group sizes and block0 offsets are multiples of 8)
    {
        GArgs ga; ga.n = 3;
        ga.g[0] = { sent,  nullptr, w1s, ps, nullptr, nullptr, nullptr, nullptr, nullptr, nullptr,
                    10240, 512, 4096, 4096, 0, 4, 0,   320, 2 };
        ga.g[1] = { f_obj, nullptr, w1o, po, nullptr, nullptr, nullptr, nullptr, nullptr, nullptr,
                    10240, 128, 1024, 1024, 0, 1, 640, 80,  2 };
        ga.g[2] = { body,  nullptr, w1b, pb, nullptr, nullptr, nullptr, nullptr, nullptr, nullptr,
                    1024,  256, 2048, 2048, 0, 2, 800, 16,  2 };
        gemm_grouped<<<832, 256, 0, stream>>>(ga);
    }

    // ---- 2b) BN + ReLU + bf16 convert of partial sums -> h_s/h_o/h_b ----
    {
        FArgs fa;
        fa.s[0] = { ps, h_s, nullptr, nullptr, g_s, b_s, m_s, v_s, 512 };
        fa.s[1] = { po, h_o, nullptr, nullptr, g_o, b_o, m_o, v_o, 128 };
        fa.s[2] = { pb, h_b, nullptr, nullptr, g_b, b_b, m_b, v_b, 256 };
        fa.off[0] = 0;
        fa.off[1] = 10240 * 512 / 4;
        fa.off[2] = fa.off[1] + 10240 * 128 / 4;
        fa.off[3] = fa.off[2] + 1024 * 256 / 4;
        bn_finalize<<<(fa.off[3] + 255) / 256, 256, 0, stream>>>(fa);
    }

    // ---- 3) stage-2 grouped GEMM (bf16 A; fp32 out) ----
    {
        GArgs ga; ga.n = 3;
        ga.g[0] = { nullptr, h_s, w2s, sen_f, nullptr, nullptr, nullptr, nullptr, nullptr, nullptr,
                    10240, 128, 512, 512, 0, 1, 0,   80, 1 };
        ga.g[1] = { nullptr, h_o, w2o, obj_f, nullptr, nullptr, nullptr, nullptr, nullptr, nullptr,
                    10240, 128, 128, 128, 0, 1, 80,  80, 1 };
        ga.g[2] = { nullptr, h_b, w2b, bod_f, nullptr, nullptr, nullptr, nullptr, nullptr, nullptr,
                    1024,  128, 256, 256, 0, 1, 160, 8,  1 };
        gemm_grouped<<<168, 256, 0, stream>>>(ga);
    }

    // ---- 4) fused attention + sum over N ----
    attn_kernel<<<1024, 256, 0, stream>>>(obj_f, bbox, word, sen_f, bod_f,
                                          Wc1, Wc2, Wsa, xsum_f);

    // ---- 5) fc1 (+bias, BN, ReLU), K=688 zero-padded to 704 (W-pad only;
    //      A overreads past row end multiply W zeros -> contribute 0) ----
    {
        GArgs ga; ga.n = 1;
        ga.g[0] = { xsum_f, nullptr, wfp, out, nullptr, bf, g_f, b_f, m_f, v_f,
                    1024, 256, 704, 688, 1, 2, 0, 16, 1 };
        gemm_grouped<<<16, 256, 0, stream>>>(ga);
    }
}

// Round 9
// 495.504 us; speedup vs baseline: 1.1241x; 1.0344x over previous
//
#include <hip/hip_runtime.h>
#include <hip/hip_bf16.h>
#include <math.h>

typedef __attribute__((ext_vector_type(8))) short short8;   // 8 x bf16 (4 VGPRs)
typedef __attribute__((ext_vector_type(4))) float floatx4;  // MFMA C/D frag

static __device__ __forceinline__ unsigned short f2bf(float f) {
    unsigned int u = __float_as_uint(f);
    unsigned int r = (u + 0x7fffu + ((u >> 16) & 1u)) >> 16;   // RNE
    return (unsigned short)r;
}

// packed fp32x2 -> bf16x2 (RNE), single VALU inst (no builtin on gfx950)
static __device__ __forceinline__ unsigned int pk_bf16(float lo, float hi) {
    unsigned int r;
    asm("v_cvt_pk_bf16_f32 %0, %1, %2" : "=v"(r) : "v"(lo), "v"(hi));
    return r;
}

// async 16B global -> LDS copy (lds dest = wave-uniform base + lane*16)
static __device__ __forceinline__ void g2l16(const void* g, void* l) {
    __builtin_amdgcn_global_load_lds(
        (const __attribute__((address_space(1))) unsigned int*)g,
        (__attribute__((address_space(3))) unsigned int*)l,
        16, 0, 0);
}

static __device__ __forceinline__ float4 bnrelu4(float4 v, float4 s, float4 h) {
    float4 r;
    r.x = fmaxf(v.x * s.x + h.x, 0.f);
    r.y = fmaxf(v.y * s.y + h.y, 0.f);
    r.z = fmaxf(v.z * s.z + h.z, 0.f);
    r.w = fmaxf(v.w * s.w + h.w, 0.f);
    return r;
}

// ---------------------------------------------------------------------------
// Grouped bf16 MFMA GEMM, double-buffered, optional split-K.
//   C[M,N] = A[M,K] @ W[N,K]^T
// A modes:
//   fp32 (afp): staged RAW into LDS via g2l16 (XOR-swizzled source),
//     converted bf16 via v_cvt_pk_bf16_f32 during fragment load.
//     fuseA==1: additionally apply per-k-channel BN+ReLU before pack.
//     NOTE: BN tables are indexed by the TRUE k of the data (kl + qd*8),
//     not the swizzled LDS slot address (r8 bug).
//   bf16 (Ab): g2l16 path, XOR-swizzled.
// T2 swizzle (rule #21, source+read, LDS linear):
//   fp32 tile [128][8 slots]: src slot (l&7)^(l>>3); read slot g^(r&7)
//   bf16 tile [128][4 slots]: src slot (c&3)^((c>>3)&3); read slot g^((r>>1)&3)
// ksplit==1: epilogue optional bias+BN+ReLU, writes fp32/bf16.
// ksplit>1 : atomicAdd fp32 partial into Cf (pre-zeroed).
// Tiles: 128x128, 4 waves. XCD-chunked blockid swizzle per group.
// ---------------------------------------------------------------------------
struct GDesc {
    const float*          Af;    // fp32 A (or null)
    const unsigned short* Ab;    // bf16 A (or null)
    const unsigned short* W;     // bf16 W, row stride = K
    float*          Cf;          // fp32 out / partial accum (or null)
    unsigned short* Cb;          // bf16 out (or null)
    const float *bias, *g, *b, *m, *v;   // epilogue BN (fuse) or A-side BN (fuseA)
    int M, N, K;                 // K = padded to mult of 32 (W stride)
    int Kreal;                   // A row stride (= K unless padded)
    int fuse;                    // 1: output BN+ReLU (ksplit==1 only)
    int nbx;                     // N / 128
    int block0;                  // first flat block id of this group
    int nbb;                     // blocks per k-chunk = nbx * (M/128)
    int ksplit;                  // #k-chunks (1 = no split)
    int fuseA;                   // 1: input-BN+ReLU on fp32 A (Kc<=256)
};
struct GArgs { GDesc g[3]; int n; };

__global__ __launch_bounds__(256)
void gemm_grouped(GArgs ga)
{
    // fp32 A tiles: 2 x 16 KB; bf16-A path aliases the first 16 KB
    __shared__ float          As_f[2][4096];
    __shared__ unsigned short Bs[2][4096];   // 2 x 8 KB
    __shared__ float scL[256], shL[256];     // A-side BN (fuseA)
    unsigned short* As_b = (unsigned short*)&As_f[0][0];  // [2][4096] ushorts

    const int bid = blockIdx.x;
    int gi = 0;
    #pragma unroll
    for (int i = 1; i < 3; ++i)
        if (i < ga.n && bid >= ga.g[i].block0) gi = i;
    const GDesc d = ga.g[gi];

    int local = bid - d.block0;
    // XCD-chunked swizzle: consecutive work items land on one XCD
    {
        const int cpx = (d.nbb * d.ksplit) >> 3;
        local = (local & 7) * cpx + (local >> 3);
    }
    int kc = 0;
    int Kc = d.K;
    if (d.ksplit > 1) {
        Kc = d.K / d.ksplit;
        kc = local / d.nbb;
        local -= kc * d.nbb;
    }
    const int kbeg = kc * Kc;
    const int bx = local % d.nbx;
    const int by = local / d.nbx;
    const int row0 = by * 128;
    const int col0 = bx * 128;

    const int tid  = threadIdx.x;
    const int wave = tid >> 6;
    const int lane = tid & 63;
    const int qd   = lane >> 4;
    const int ln   = lane & 15;
    const int wr   = (wave >> 1) * 64;
    const int wc   = (wave & 1) * 64;

    // bf16 g2l16 chunk mapping: chunk c -> row c>>2, source 16B-slot
    const int c0 = wave * 128 + lane;
    const int c1 = c0 + 64;
    const int r0 = c0 >> 2, k0 = (((c0 & 3) ^ ((c0 >> 3) & 3))) * 8;
    const int r1 = c1 >> 2, k1 = (((c1 & 3) ^ ((c1 >> 3) & 3))) * 8;

    // fp32-A g2l16 mapping: row wave*32+t*8+(l>>3), src col ((l&7)^(l>>3))*4
    const int aro  = wave * 32 + (lane >> 3);  // + t*8
    const int acol = ((lane & 7) ^ (lane >> 3)) * 4;

    const bool afp = (d.Af != nullptr);
    const int niter = Kc >> 5;

    floatx4 acc[4][4];
    #pragma unroll
    for (int i = 0; i < 4; ++i)
        #pragma unroll
        for (int j = 0; j < 4; ++j) acc[i][j] = (floatx4){0.f, 0.f, 0.f, 0.f};

    // ---- prologue: A-side BN tables + stage tile 0 into buffer 0 ----
    if (d.fuseA) {
        for (int k = tid; k < Kc; k += 256) {
            float sc = d.g[kbeg + k] * rsqrtf(d.v[kbeg + k] + 1e-5f);
            scL[k] = sc;
            shL[k] = d.b[kbeg + k] - d.m[kbeg + k] * sc;
        }
    }
    g2l16(d.W + (size_t)(col0 + r0) * d.K + kbeg + k0, &Bs[0][(size_t)wave * 1024]);
    g2l16(d.W + (size_t)(col0 + r1) * d.K + kbeg + k1, &Bs[0][(size_t)wave * 1024 + 512]);
    if (afp) {
        #pragma unroll
        for (int t = 0; t < 4; ++t)
            g2l16(d.Af + (size_t)(row0 + aro + t * 8) * d.Kreal + kbeg + acol,
                  &As_f[0][(size_t)(wave * 4 + t) * 256]);
    } else {
        g2l16(d.Ab + (size_t)(row0 + r0) * d.K + kbeg + k0, As_b + (size_t)wave * 1024);
        g2l16(d.Ab + (size_t)(row0 + r1) * d.K + kbeg + k1, As_b + (size_t)wave * 1024 + 512);
    }
    __syncthreads();

    int cur = 0;
    for (int it = 0; it < niter; ++it) {
        const int nxt = cur ^ 1;
        const bool pf = (it + 1 < niter);

        if (pf) {
            const int kg = kbeg + (it + 1) * 32;
            g2l16(d.W + (size_t)(col0 + r0) * d.K + kg + k0, &Bs[nxt][(size_t)wave * 1024]);
            g2l16(d.W + (size_t)(col0 + r1) * d.K + kg + k1, &Bs[nxt][(size_t)wave * 1024 + 512]);
            if (afp) {
                #pragma unroll
                for (int t = 0; t < 4; ++t)
                    g2l16(d.Af + (size_t)(row0 + aro + t * 8) * d.Kreal + kg + acol,
                          &As_f[nxt][(size_t)(wave * 4 + t) * 256]);
            } else {
                g2l16(d.Ab + (size_t)(row0 + r0) * d.K + kg + k0, As_b + (size_t)nxt * 4096 + wave * 1024);
                g2l16(d.Ab + (size_t)(row0 + r1) * d.K + kg + k1, As_b + (size_t)nxt * 4096 + wave * 1024 + 512);
            }
        }

        // ---- compute on current buffer (swizzled reads) ----
        short8 a[4], b[4];
        if (afp) {
            const int kl = it * 32;
            #pragma unroll
            for (int i = 0; i < 4; ++i) {
                const int row = wr + i * 16 + ln;
                const int sw  = row & 7;
                const int c0f = ((qd * 2)     ^ sw) * 4;   // LDS addr of true k = qd*8
                const int c1f = ((qd * 2 + 1) ^ sw) * 4;   // LDS addr of true k = qd*8+4
                float4 v0 = *(const float4*)&As_f[cur][row * 32 + c0f];
                float4 v1 = *(const float4*)&As_f[cur][row * 32 + c1f];
                if (d.fuseA) {
                    const int kf = kl + qd * 8;            // TRUE k of v0 (not LDS addr)
                    v0 = bnrelu4(v0, *(const float4*)&scL[kf],
                                     *(const float4*)&shL[kf]);
                    v1 = bnrelu4(v1, *(const float4*)&scL[kf + 4],
                                     *(const float4*)&shL[kf + 4]);
                }
                int4 pk = { (int)pk_bf16(v0.x, v0.y), (int)pk_bf16(v0.z, v0.w),
                            (int)pk_bf16(v1.x, v1.y), (int)pk_bf16(v1.z, v1.w) };
                a[i] = *(short8*)&pk;
            }
        } else {
            #pragma unroll
            for (int i = 0; i < 4; ++i) {
                const int row = wr + i * 16 + ln;
                const int sw  = (row >> 1) & 3;
                a[i] = *(const short8*)&As_b[(size_t)cur * 4096 + row * 32 + (qd ^ sw) * 8];
            }
        }
        #pragma unroll
        for (int j = 0; j < 4; ++j) {
            const int row = wc + j * 16 + ln;
            const int sw  = (row >> 1) & 3;
            b[j] = *(const short8*)&Bs[cur][row * 32 + (qd ^ sw) * 8];
        }
        #pragma unroll
        for (int i = 0; i < 4; ++i)
            #pragma unroll
            for (int j = 0; j < 4; ++j)
                acc[i][j] = __builtin_amdgcn_mfma_f32_16x16x32_bf16(
                                a[i], b[j], acc[i][j], 0, 0, 0);

        __syncthreads();
        cur = nxt;
    }

    // ---- epilogue: C/D layout col = lane&15, row = quad*4 + reg ----
    if (d.ksplit > 1) {
        #pragma unroll
        for (int j = 0; j < 4; ++j) {
            const int col = col0 + wc + j * 16 + ln;
            #pragma unroll
            for (int i = 0; i < 4; ++i) {
                #pragma unroll
                for (int r = 0; r < 4; ++r) {
                    const int row = row0 + wr + i * 16 + qd * 4 + r;
                    atomicAdd(&d.Cf[(size_t)row * d.N + col], acc[i][j][r]);
                }
            }
        }
        return;
    }

    #pragma unroll
    for (int j = 0; j < 4; ++j) {
        const int col = col0 + wc + j * 16 + ln;
        float add = d.bias ? d.bias[col] : 0.f;
        float scale = 1.f, shift = 0.f;
        if (d.fuse) {
            scale = d.g[col] * rsqrtf(d.v[col] + 1e-5f);
            shift = d.b[col] - d.m[col] * scale;
        }
        #pragma unroll
        for (int i = 0; i < 4; ++i) {
            #pragma unroll
            for (int r = 0; r < 4; ++r) {
                const int row = row0 + wr + i * 16 + qd * 4 + r;
                float vv = acc[i][j][r] + add;
                if (d.fuse) vv = fmaxf(vv * scale + shift, 0.f);
                if (d.Cf) d.Cf[(size_t)row * d.N + col] = vv;
                if (d.Cb) d.Cb[(size_t)row * d.N + col] = f2bf(vv);
            }
        }
    }
}

// ---------------------------------------------------------------------------
// Prep kernel: 6 GEMM weight matrices fp32 -> bf16; Wf -> packed-transposed
// u32[352][256] (pair of bf16 per u32, k ascending); zero-fill the atomic-
// accumulator span (stage-1 partials + stage-2 outputs), one launch.
// ---------------------------------------------------------------------------
struct WSeg { const float* src; void* dst; int Kreal; int Kp; };
struct WArgs { WSeg s[7]; int off[8]; float4* zdst; int zn; };

__global__ __launch_bounds__(256)
void cvt_weights(WArgs wa)
{
    int i = blockIdx.x * 256 + threadIdx.x;
    if (i >= wa.off[7]) {
        int z = i - wa.off[7];
        if (z < wa.zn) wa.zdst[z] = (float4){0.f, 0.f, 0.f, 0.f};
        return;
    }
    int s = 0;
    #pragma unroll
    for (int j = 1; j < 7; ++j) if (i >= wa.off[j]) s = j;
    const WSeg sg = wa.s[s];
    const int li = i - wa.off[s];
    if (s == 6) {
        // Wf[256][688] -> packed [352][256]: dst[k2*256+c] = bf16(Wf[c][2k2+1])<<16 | bf16(Wf[c][2k2])
        const int k2 = li >> 8, c = li & 255;
        const int ka = k2 * 2, kb = k2 * 2 + 1;
        unsigned int lo = (ka < 688) ? f2bf(sg.src[(size_t)c * 688 + ka]) : 0u;
        unsigned int hi = (kb < 688) ? f2bf(sg.src[(size_t)c * 688 + kb]) : 0u;
        ((unsigned int*)sg.dst)[li] = lo | (hi << 16);
        return;
    }
    const int r = li / sg.Kp, c = li - r * sg.Kp;
    ((unsigned short*)sg.dst)[li] =
        (c < sg.Kreal) ? f2bf(sg.src[(size_t)r * sg.Kreal + c]) : (unsigned short)0;
}

// ---------------------------------------------------------------------------
// Fused attention (per batch row): channel attn (N=10) + spatial conv k=7 +
// weighted sum over N + fc1 (bias+BN+ReLU) -> out[b][256]
// ---------------------------------------------------------------------------
__global__ __launch_bounds__(256)
void attn_kernel(const float* __restrict__ obj, const float* __restrict__ bbox,
                 const float* __restrict__ word, const float* __restrict__ sen,
                 const float* __restrict__ bod,
                 const float* __restrict__ Wc1, const float* __restrict__ Wc2,
                 const float* __restrict__ Wsa,
                 const unsigned int* __restrict__ wfpk,
                 const float* __restrict__ bf,
                 const float* __restrict__ g_f, const float* __restrict__ b_f,
                 const float* __restrict__ m_f, const float* __restrict__ v_f,
                 float* __restrict__ out)
{
    const int b = blockIdx.x;
    const int tid = threadIdx.x;

    __shared__ float xs[10][688];
    __shared__ float s0[688], s1[688];
    __shared__ float xr[688];
    __shared__ float avec[10], mvec[10], att[10];
    __shared__ float cw[14], c1[50], c2[50];

    if (tid < 14) cw[tid] = Wsa[tid];
    if (tid < 50) { c1[tid] = Wc1[tid]; c2[tid] = Wc2[tid]; }

    for (int n = 0; n < 10; ++n) {
        const float* o  = obj  + ((size_t)b * 10 + n) * 128;
        const float* bx = bbox + ((size_t)b * 10 + n) * 4;
        const float* w  = word + ((size_t)b * 10 + n) * 300;
        const float* s  = sen  + ((size_t)b * 10 + n) * 128;
        const float* bo = bod  + (size_t)b * 128;
        for (int c = tid; c < 688; c += 256) {
            float v;
            if      (c < 128) v = o[c];
            else if (c < 132) v = bx[c - 128];
            else if (c < 432) v = w[c - 132];
            else if (c < 560) v = s[c - 432];
            else              v = bo[c - 560];
            xs[n][c] = v;
        }
    }
    __syncthreads();

    // wave-parallel per-row mean/max: wave w handles rows w, w+4, w+8
    {
        const int wv = tid >> 6, ln2 = tid & 63;
        for (int n = wv; n < 10; n += 4) {
            float sm = 0.f, mx = -INFINITY;
            for (int c = ln2; c < 688; c += 64) {
                float v = xs[n][c];
                sm += v; mx = fmaxf(mx, v);
            }
            #pragma unroll
            for (int off = 32; off > 0; off >>= 1) {
                sm += __shfl_down(sm, off);
                mx = fmaxf(mx, __shfl_down(mx, off));
            }
            if (ln2 == 0) { avec[n] = sm * (1.f / 688.f); mvec[n] = mx; }
        }
    }
    __syncthreads();

    if (tid == 0) {
        float ha[5], hm[5];
        #pragma unroll
        for (int i = 0; i < 5; ++i) {
            float sa_ = 0.f, sm_ = 0.f;
            #pragma unroll
            for (int j = 0; j < 10; ++j) {
                sa_ += c1[i * 10 + j] * avec[j];
                sm_ += c1[i * 10 + j] * mvec[j];
            }
            ha[i] = fmaxf(sa_, 0.f);
            hm[i] = fmaxf(sm_, 0.f);
        }
        #pragma unroll
        for (int j = 0; j < 10; ++j) {
            float v = 0.f;
            #pragma unroll
            for (int i = 0; i < 5; ++i) v += c2[j * 5 + i] * (ha[i] + hm[i]);
            att[j] = 1.f / (1.f + expf(-v));
        }
    }
    __syncthreads();

    for (int c = tid; c < 688; c += 256) {
        float sm = 0.f, mx = -INFINITY;
        #pragma unroll
        for (int n = 0; n < 10; ++n) {
            float v = xs[n][c] * att[n];
            xs[n][c] = v;
            sm += v; mx = fmaxf(mx, v);
        }
        s0[c] = sm * 0.1f;
        s1[c] = mx;
    }
    __syncthreads();

    for (int c = tid; c < 688; c += 256) {
        float sa = 0.f;
        #pragma unroll
        for (int j = 0; j < 7; ++j) {
            int cc = c + j - 3;
            if (cc >= 0 && cc < 688)
                sa += cw[j] * s0[cc] + cw[7 + j] * s1[cc];
        }
        float sig = 1.f / (1.f + expf(-sa));
        float sm = 0.f;
        #pragma unroll
        for (int n = 0; n < 10; ++n) sm += xs[n][c];
        xr[c] = sm * sig;
    }
    __syncthreads();

    // ---- fused fc1: out[b][tid] = ReLU(BN(dot(xr, Wf[tid]) + bf[tid])) ----
    {
        float acc = 0.f;
        #pragma unroll 4
        for (int k2 = 0; k2 < 344; ++k2) {
            unsigned int w2 = wfpk[(size_t)k2 * 256 + tid];
            float wlo = __uint_as_float(w2 << 16);
            float whi = __uint_as_float(w2 & 0xffff0000u);
            acc += wlo * xr[2 * k2] + whi * xr[2 * k2 + 1];
        }
        float sc = g_f[tid] * rsqrtf(v_f[tid] + 1e-5f);
        float sh = b_f[tid] - m_f[tid] * sc;
        out[(size_t)b * 256 + tid] = fmaxf((acc + bf[tid]) * sc + sh, 0.f);
    }
}

// ---------------------------------------------------------------------------
extern "C" void kernel_launch(void* const* d_in, const int* in_sizes, int n_in,
                              void* d_out, int out_size, void* d_ws, size_t ws_size,
                              hipStream_t stream)
{
    const float* f_obj = (const float*)d_in[0];
    const float* bbox  = (const float*)d_in[1];
    const float* word  = (const float*)d_in[2];
    const float* sent  = (const float*)d_in[3];
    const float* body  = (const float*)d_in[4];
    const float* W1_o  = (const float*)d_in[5];
    const float* g_o = (const float*)d_in[6],  *b_o = (const float*)d_in[7];
    const float* m_o = (const float*)d_in[8],  *v_o = (const float*)d_in[9];
    const float* W2_o  = (const float*)d_in[10];
    const float* W1_s  = (const float*)d_in[11];
    const float* g_s = (const float*)d_in[12], *b_s = (const float*)d_in[13];
    const float* m_s = (const float*)d_in[14], *v_s = (const float*)d_in[15];
    const float* W2_s  = (const float*)d_in[16];
    const float* W1_b  = (const float*)d_in[17];
    const float* g_b = (const float*)d_in[18], *b_b = (const float*)d_in[19];
    const float* m_b = (const float*)d_in[20], *v_b = (const float*)d_in[21];
    const float* W2_b  = (const float*)d_in[22];
    const float* Wc1 = (const float*)d_in[23];
    const float* Wc2 = (const float*)d_in[24];
    const float* Wsa = (const float*)d_in[25];
    const float* Wf  = (const float*)d_in[26];
    const float* bf  = (const float*)d_in[27];
    const float* g_f = (const float*)d_in[28], *b_f = (const float*)d_in[29];
    const float* m_f = (const float*)d_in[30], *v_f = (const float*)d_in[31];
    float* out = (float*)d_out;

    // ---- workspace carve (~44.4 MB) ----
    char* p = (char*)d_ws;
    unsigned short* w1s  = (unsigned short*)p; p += 4194304;   // 512*4096
    unsigned short* w2s  = (unsigned short*)p; p += 131072;    // 128*512
    unsigned short* w1o  = (unsigned short*)p; p += 262144;    // 128*1024
    unsigned short* w2o  = (unsigned short*)p; p += 32768;     // 128*128
    unsigned short* w1b  = (unsigned short*)p; p += 1048576;   // 256*2048
    unsigned short* w2b  = (unsigned short*)p; p += 65536;     // 128*256
    unsigned int*   wfpk = (unsigned int*)p;   p += 360448;    // 352*256 u32
    // contiguous zero span: stage-2 atomic outputs + stage-1 partials
    char* zbase = p;
    float* sen_f = (float*)p; p += 5242880;                    // 10240*128 f32
    float* obj_f = (float*)p; p += 5242880;                    // 10240*128 f32
    float* bod_f = (float*)p; p += 524288;                     // 1024*128 f32
    float* ps    = (float*)p; p += 20971520;                   // 10240*512 f32
    float* po    = (float*)p; p += 5242880;                    // 10240*128 f32
    float* pb    = (float*)p; p += 1048576;                    // 1024*256 f32
    const int zbytes = 38273024;                               // sen_f..pb
    if ((size_t)(p - (char*)d_ws) > ws_size) return;

    // ---- 1) weights -> bf16 / packed Wf + zero atomic span, one launch ----
    WArgs wa;
    wa.s[0] = { W1_s, w1s,  4096, 4096 };
    wa.s[1] = { W2_s, w2s,   512,  512 };
    wa.s[2] = { W1_o, w1o,  1024, 1024 };
    wa.s[3] = { W2_o, w2o,   128,  128 };
    wa.s[4] = { W1_b, w1b,  2048, 2048 };
    wa.s[5] = { W2_b, w2b,   256,  256 };
    wa.s[6] = { Wf,   wfpk,  688,  704 };   // packed-transposed (special-cased)
    const int wn[7] = { 512*4096, 128*512, 128*1024, 128*128, 256*2048, 128*256, 352*256 };
    wa.off[0] = 0;
    for (int i = 0; i < 7; ++i) wa.off[i + 1] = wa.off[i] + wn[i];
    wa.zdst = (float4*)zbase;
    wa.zn   = zbytes / 16;
    cvt_weights<<<(wa.off[7] + wa.zn + 255) / 256, 256, 0, stream>>>(wa);

    // ---- 2) stage-1 grouped GEMM, split-K x2, async fp32-A staging ----
    //      grid: sent 2*320 + obj 2*80 + body 2*16 = 832 blocks
    {
        GArgs ga; ga.n = 3;
        ga.g[0] = { sent,  nullptr, w1s, ps, nullptr, nullptr, nullptr, nullptr, nullptr, nullptr,
                    10240, 512, 4096, 4096, 0, 4, 0,   320, 2, 0 };
        ga.g[1] = { f_obj, nullptr, w1o, po, nullptr, nullptr, nullptr, nullptr, nullptr, nullptr,
                    10240, 128, 1024, 1024, 0, 1, 640, 80,  2, 0 };
        ga.g[2] = { body,  nullptr, w1b, pb, nullptr, nullptr, nullptr, nullptr, nullptr, nullptr,
                    1024,  256, 2048, 2048, 0, 2, 800, 16,  2, 0 };
        gemm_grouped<<<832, 256, 0, stream>>>(ga);
    }

    // ---- 3) stage-2 grouped GEMM: fp32 partials as A with fused input-
    //      BN+ReLU (former bn_finalize), split-K x2, atomic fp32 outputs ----
    {
        GArgs ga; ga.n = 3;
        ga.g[0] = { ps, nullptr, w2s, sen_f, nullptr, nullptr, g_s, b_s, m_s, v_s,
                    10240, 128, 512, 512, 0, 1, 0,   80, 2, 1 };
        ga.g[1] = { po, nullptr, w2o, obj_f, nullptr, nullptr, g_o, b_o, m_o, v_o,
                    10240, 128, 128, 128, 0, 1, 160, 80, 2, 1 };
        ga.g[2] = { pb, nullptr, w2b, bod_f, nullptr, nullptr, g_b, b_b, m_b, v_b,
                    1024,  128, 256, 256, 0, 1, 320, 8,  2, 1 };
        gemm_grouped<<<336, 256, 0, stream>>>(ga);
    }

    // ---- 4) fused attention + sum over N + fc1 -> out ----
    attn_kernel<<<1024, 256, 0, stream>>>(obj_f, bbox, word, sen_f, bod_f,
                                          Wc1, Wc2, Wsa, wfpk, bf,
                                          g_f, b_f, m_f, v_f, out);
}